// Round 13
// baseline (1094.849 us; speedup 1.0000x reference)
//
#include <hip/hip_runtime.h>
#include <hip/hip_bf16.h>

#define NN 200000
#define EE 400000
#define HDIM 256
#define LL 4
#define FEAT 10

#if defined(__has_builtin)
#if __has_builtin(__builtin_amdgcn_cvt_pk_fp8_f32) && __has_builtin(__builtin_amdgcn_cvt_pk_f32_fp8)
#define HAVE_FP8 1
#endif
#endif
#ifndef HAVE_FP8
#define HAVE_FP8 0
#endif

typedef unsigned short ushort_t;
typedef __attribute__((ext_vector_type(8))) short bf16x8;
typedef __attribute__((ext_vector_type(8))) unsigned short u16x8;
typedef __attribute__((ext_vector_type(2))) float f32x2;
typedef __attribute__((ext_vector_type(4))) float f32x4;
typedef __attribute__((ext_vector_type(4))) unsigned int u32x4;

__device__ inline ushort_t f2bf(float f) {
    unsigned int u = __builtin_bit_cast(unsigned int, f);
    return (ushort_t)((u + 0x7fffu + ((u >> 16) & 1u)) >> 16);
}
__device__ inline float bf2f(ushort_t s) {
    unsigned int u = ((unsigned int)s) << 16;
    return __builtin_bit_cast(float, u);
}
__device__ inline float silu_f(float v) { return v / (1.0f + __expf(-v)); }

// x/U global layout PRE-SWIZZLED: row n, 16B-chunk slot s holds true chunk s ^ (n&7).

// ---------------- node init: xb = LN(silu(emb[z] + feat@Wf + bf)); 32 lanes/node
__global__ __launch_bounds__(256) void node_init_kernel(
    const int* __restrict__ z, const float* __restrict__ feat,
    const float* __restrict__ emb, const float* __restrict__ Wf,
    const float* __restrict__ bfv, const float* __restrict__ g0,
    const float* __restrict__ b0, ushort_t* __restrict__ xb)
{
    int n = blockIdx.x * 8 + (threadIdx.x >> 5);
    int nl = threadIdx.x & 31, c0 = nl * 8;
    int zi = z[n];
    float a[8];
    {
        f32x4 e0 = *(const f32x4*)&emb[(size_t)zi * HDIM + c0];
        f32x4 e1 = *(const f32x4*)&emb[(size_t)zi * HDIM + c0 + 4];
        f32x4 v0 = *(const f32x4*)&bfv[c0];
        f32x4 v1 = *(const f32x4*)&bfv[c0 + 4];
        #pragma unroll
        for (int j = 0; j < 4; ++j) { a[j] = e0[j] + v0[j]; a[4 + j] = e1[j] + v1[j]; }
    }
    #pragma unroll
    for (int f = 0; f < FEAT; ++f) {
        float sf = feat[n * FEAT + f];
        f32x4 w0 = *(const f32x4*)&Wf[f * HDIM + c0];
        f32x4 w1 = *(const f32x4*)&Wf[f * HDIM + c0 + 4];
        #pragma unroll
        for (int j = 0; j < 4; ++j) { a[j] += sf * w0[j]; a[4 + j] += sf * w1[j]; }
    }
    float s = 0.f, q = 0.f;
    #pragma unroll
    for (int c = 0; c < 8; ++c) { a[c] = silu_f(a[c]); s += a[c]; q += a[c] * a[c]; }
    #pragma unroll
    for (int o = 16; o; o >>= 1) { s += __shfl_xor(s, o, 64); q += __shfl_xor(q, o, 64); }
    float mu = s * (1.0f / HDIM);
    float var = q * (1.0f / HDIM) - mu * mu;
    float rs = rsqrtf(var + 1e-5f);
    f32x4 g0v = *(const f32x4*)&g0[c0];
    f32x4 g1v = *(const f32x4*)&g0[c0 + 4];
    f32x4 b0v = *(const f32x4*)&b0[c0];
    f32x4 b1v = *(const f32x4*)&b0[c0 + 4];
    u16x8 o8;
    #pragma unroll
    for (int j = 0; j < 4; ++j) {
        o8[j]     = f2bf((a[j]     - mu) * rs * g0v[j] + b0v[j]);
        o8[4 + j] = f2bf((a[4 + j] - mu) * rs * g1v[j] + b1v[j]);
    }
    *(u16x8*)&xb[((size_t)n << 8) + ((nl ^ (n & 7)) << 3)] = o8;
}

__global__ __launch_bounds__(256) void batch_out_kernel(
    const int* __restrict__ batch, float* __restrict__ out)
{
    int i = blockIdx.x * 256 + threadIdx.x;
    if (i < NN) out[i] = (float)batch[i];
}

// ---------------- CSR build
__global__ __launch_bounds__(256) void hist_kernel(const int* __restrict__ ei, int* __restrict__ deg)
{
    int i = blockIdx.x * 256 + threadIdx.x;
    if (i < EE) atomicAdd(&deg[ei[EE + i]], 1);
}

__global__ __launch_bounds__(256) void scan_blocks_kernel(
    const int* __restrict__ deg, int* __restrict__ off, int* __restrict__ psum)
{
    int blk = blockIdx.x, t = threadIdx.x;
    int base = blk * 1024 + t * 4;
    int v[4];
    #pragma unroll
    for (int i = 0; i < 4; ++i) v[i] = (base + i < NN) ? deg[base + i] : 0;
    int s = v[0] + v[1] + v[2] + v[3];
    int lane = t & 63, w = t >> 6;
    int ps = s;
    #pragma unroll
    for (int o = 1; o < 64; o <<= 1) { int u = __shfl_up(ps, o, 64); if (lane >= o) ps += u; }
    __shared__ int wt[4];
    if (lane == 63) wt[w] = ps;
    __syncthreads();
    int wbase = 0;
    for (int k = 0; k < w; ++k) wbase += wt[k];
    int run = wbase + ps - s;
    #pragma unroll
    for (int i = 0; i < 4; ++i) {
        if (base + i < NN) off[base + i] = run;
        run += v[i];
    }
    if (t == 255) psum[blk] = wbase + ps;
}

__global__ __launch_bounds__(256) void scan_top_kernel(int* __restrict__ psum, int nb)
{
    int t = threadIdx.x;
    int v = (t < nb) ? psum[t] : 0;
    int lane = t & 63, w = t >> 6;
    int ps = v;
    #pragma unroll
    for (int o = 1; o < 64; o <<= 1) { int u = __shfl_up(ps, o, 64); if (lane >= o) ps += u; }
    __shared__ int wt[4];
    if (lane == 63) wt[w] = ps;
    __syncthreads();
    int wbase = 0;
    for (int k = 0; k < w; ++k) wbase += wt[k];
    if (t < nb) psum[t] = wbase + ps - v;
}

__global__ __launch_bounds__(256) void scan_add_kernel(
    int* __restrict__ off, const int* __restrict__ psum, int* __restrict__ cursor)
{
    int i = blockIdx.x * 256 + threadIdx.x;
    if (i < NN) {
        int o = off[i] + psum[i >> 10];
        off[i] = o;
        cursor[i] = o;
        if (i == NN - 1) off[NN] = EE;
    }
}

__global__ __launch_bounds__(256) void scatter_kernel(
    const int* __restrict__ ei, const float* __restrict__ ea,
    int* __restrict__ cursor, int* __restrict__ srcs, float4* __restrict__ eaf)
{
    int i = blockIdx.x * 256 + threadIdx.x;
    if (i < EE) {
        int dst = ei[EE + i];
        int pos = atomicAdd(&cursor[dst], 1);
        srcs[pos] = ei[i];
        eaf[pos] = ((const float4*)ea)[i];
    }
}

// ---------------- edge MLP (layer-invariant): e = silu(eaf@We + be), CSR order.
// fp8 (8B/lane) when available, else bf16 (16B/lane).
__global__ __launch_bounds__(256) void edge_mlp_kernel(
    const float4* __restrict__ eaf, const float* __restrict__ We,
    const float* __restrict__ be, void* __restrict__ eout)
{
    int p = (blockIdx.x * 256 + threadIdx.x) >> 5;
    if (p >= EE) return;
    int nl = threadIdx.x & 31, c0 = nl * 8;
    float4 av = eaf[p];
    float v[8];
    #pragma unroll
    for (int j = 0; j < 8; ++j) {
        float t = be[c0 + j] + av.x * We[c0 + j] + av.y * We[HDIM + c0 + j]
                + av.z * We[2 * HDIM + c0 + j] + av.w * We[3 * HDIM + c0 + j];
        v[j] = silu_f(t);
    }
#if HAVE_FP8
    int t0 = __builtin_amdgcn_cvt_pk_fp8_f32(v[0], v[1], 0, false);
    t0 = __builtin_amdgcn_cvt_pk_fp8_f32(v[2], v[3], t0, true);
    int t1 = __builtin_amdgcn_cvt_pk_fp8_f32(v[4], v[5], 0, false);
    t1 = __builtin_amdgcn_cvt_pk_fp8_f32(v[6], v[7], t1, true);
    uint2 o;
    o.x = (unsigned int)t0;
    o.y = (unsigned int)t1;
    ((uint2*)eout)[(size_t)p * 32 + nl] = o;
#else
    u16x8 o8;
    #pragma unroll
    for (int j = 0; j < 8; ++j) o8[j] = f2bf(v[j]);
    *(u16x8*)&((ushort_t*)eout)[((size_t)p << 8) + nl * 8] = o8;
#endif
}

// ---------------- weights: W[l][k][n] f32 -> chunk-major per-wave (8 col-waves) bf16
// Wc[l][c<8][w<8][nf<2][lane<64][e<8] = W[l][k=c*32+(lane>>4)*8+e][n=w*32+nf*16+(lane&15)]
// (per-lane map = MFMA A-operand fragment: row=lane&15, k=(lane>>4)*8+e)
__global__ __launch_bounds__(256) void prep_w_kernel(
    const float* __restrict__ W1, const float* __restrict__ W2,
    ushort_t* __restrict__ Wc1, ushort_t* __restrict__ Wc2)
{
    int idx = blockIdx.x * 256 + threadIdx.x;   // 2 * 4 * 65536
    int which = idx >> 18;
    int rem = idx & 0x3FFFF;
    int l = rem >> 16;
    int t = rem & 0xFFFF;
    int e = t & 7;
    int lane = (t >> 3) & 63;
    int nf = (t >> 9) & 1;
    int w8 = (t >> 10) & 7;
    int c = (t >> 13) & 7;
    int n = w8 * 32 + nf * 16 + (lane & 15);
    int k = c * 32 + (lane >> 4) * 8 + e;
    const float* W = which ? W2 : W1;
    ushort_t* Wc = which ? Wc2 : Wc1;
    Wc[rem] = f2bf(W[l * 65536 + k * 256 + n]);
}

// ---------------- aggregation: U = bf16(x_self + sum relu(x[src]+e)); 32-lane groups,
// grid-stride. USE_E=1 reads precomputed e (fp8 or bf16); USE_E=0 recomputes.
template<int USE_E>
__global__ __launch_bounds__(256) void agg_kernel(
    const int* __restrict__ off, const int* __restrict__ srcs,
    const void* __restrict__ eprec, const float4* __restrict__ eaf,
    const float* __restrict__ We, const float* __restrict__ be,
    const ushort_t* __restrict__ xin, ushort_t* __restrict__ U)
{
    const int gstride = (gridDim.x * 256) >> 5;
    const int gid0 = (blockIdx.x * 256 + threadIdx.x) >> 5;
    const int nl = threadIdx.x & 31, c0 = nl * 8;
    float wv[4][8], bev[8];
    if (!USE_E) {
        #pragma unroll
        for (int r4 = 0; r4 < 4; ++r4)
            #pragma unroll
            for (int j = 0; j < 8; ++j) wv[r4][j] = We[r4 * HDIM + c0 + j];
        #pragma unroll
        for (int j = 0; j < 8; ++j) bev[j] = be[c0 + j];
    }

    for (int n = gid0; n < NN; n += gstride) {
        u16x8 xs = *(const u16x8*)&xin[((size_t)n << 8) + ((nl ^ (n & 7)) << 3)];
        float acc[8];
        #pragma unroll
        for (int j = 0; j < 8; ++j) acc[j] = bf2f(xs[j]);
        int beg = off[n], end = off[n + 1];
        if (USE_E) {
            for (int p = beg; p < end; ++p) {
                int src = srcs[p];
                u16x8 xg = *(const u16x8*)&xin[((size_t)src << 8) + ((nl ^ (src & 7)) << 3)];
#if HAVE_FP8
                uint2 eg = ((const uint2*)eprec)[(size_t)p * 32 + nl];
                f32x2 e01 = __builtin_amdgcn_cvt_pk_f32_fp8((int)eg.x, false);
                f32x2 e23 = __builtin_amdgcn_cvt_pk_f32_fp8((int)eg.x, true);
                f32x2 e45 = __builtin_amdgcn_cvt_pk_f32_fp8((int)eg.y, false);
                f32x2 e67 = __builtin_amdgcn_cvt_pk_f32_fp8((int)eg.y, true);
                float ev[8] = {e01[0], e01[1], e23[0], e23[1],
                               e45[0], e45[1], e67[0], e67[1]};
#else
                u16x8 eg = *(const u16x8*)&((const ushort_t*)eprec)[((size_t)p << 8) + nl * 8];
                float ev[8];
                #pragma unroll
                for (int j = 0; j < 8; ++j) ev[j] = bf2f(eg[j]);
#endif
                #pragma unroll
                for (int j = 0; j < 8; ++j)
                    acc[j] += fmaxf(bf2f(xg[j]) + ev[j], 0.f);
            }
        } else {
            for (int p = beg; p < end; ++p) {
                int src = srcs[p];
                float4 av = eaf[p];
                u16x8 xg = *(const u16x8*)&xin[((size_t)src << 8) + ((nl ^ (src & 7)) << 3)];
                #pragma unroll
                for (int j = 0; j < 8; ++j) {
                    float e = silu_f(bev[j] + av.x * wv[0][j] + av.y * wv[1][j]
                                            + av.z * wv[2][j] + av.w * wv[3][j]);
                    acc[j] += fmaxf(bf2f(xg[j]) + e, 0.f);
                }
            }
        }
        u16x8 o8;
        #pragma unroll
        for (int j = 0; j < 8; ++j) o8[j] = f2bf(acc[j]);
        *(u16x8*)&U[((size_t)n << 8) + ((nl ^ (n & 7)) << 3)] = o8;
    }
}

// ---------------- MLP + LN: out = LN(xin + (silu(U@W1+b1))@W2 + b2)
// 64 rows/block, 512 thr (8 col-waves of 32 cols). Weights in registers (dbuf +
// 1-chunk prefetch) as MFMA *A* operand (D row = weight-n, D col = U-row) so the
// t/h phases are aligned ds_write_b64. __launch_bounds__(512,8): 8 waves/SIMD
// -> 4 blocks/CU (LDS 4x34.8KB=139KB, VGPR<=64). xout aliases U (own rows only).
template<int LAST>
__global__ __launch_bounds__(512, 8) void mlp_kernel(
    const ushort_t* U, const ushort_t* __restrict__ Wc1,
    const ushort_t* __restrict__ Wc2, const float* __restrict__ b1,
    const float* __restrict__ b2, const float* __restrict__ lng,
    const float* __restrict__ lnb, const ushort_t* __restrict__ xin,
    ushort_t* xout, float* __restrict__ xf32)
{
    __shared__ ushort_t sA[64][256];     // 32KB: U -> t -> h/v (swizzled cells)
    __shared__ float sGB[2][HDIM];       // 2KB gamma/beta
    const int tid = threadIdx.x;
    const int m0 = blockIdx.x * 64;
    const int lane = tid & 63;
    const int w = tid >> 6;
    const int lg = lane >> 4, ll = lane & 15;
    const int cb = w * 32;

    if (tid < HDIM) sGB[0][tid] = lng[tid];
    else sGB[1][tid - HDIM] = lnb[tid - HDIM];

    // bias vectors over n = cb + nf*16 + lg*4 + j  (4 consecutive)
    f32x4 bv1v[2], bv2v[2];
    #pragma unroll
    for (int nf = 0; nf < 2; ++nf) {
        int nb = cb + nf * 16 + lg * 4;
        bv1v[nf] = *(const f32x4*)&b1[nb];
        bv2v[nf] = *(const f32x4*)&b2[nb];
    }

    // ---- stage U tile (linear; global pre-swizzled)
    #pragma unroll
    for (int it = 0; it < 4; ++it) {
        int idx = tid + it * 512;
        *(u32x4*)((ushort_t*)sA + (idx << 3)) =
            *(const u32x4*)(U + (((size_t)m0) << 8) + (idx << 3));
    }
    __syncthreads();

    f32x4 acc[4][2] = {};
    const ushort_t* wp1 = Wc1 + w * 1024 + lane * 8;
    const ushort_t* wp2 = Wc2 + w * 1024 + lane * 8;
    bf16x8 wbuf[2][2];
    wbuf[0][0] = *(const bf16x8*)(wp1);
    wbuf[0][1] = *(const bf16x8*)(wp1 + 512);

    // ---- GEMM1 (reg prefetch; last iter prefetches W2 chunk0); W as A-operand
    #pragma unroll
    for (int p = 0; p < 8; ++p) {
        const ushort_t* nsrc = (p < 7) ? (wp1 + (p + 1) * 8192) : wp2;
        wbuf[(p + 1) & 1][0] = *(const bf16x8*)(nsrc);
        wbuf[(p + 1) & 1][1] = *(const bf16x8*)(nsrc + 512);
        bf16x8 af[4];
        #pragma unroll
        for (int m = 0; m < 4; ++m) {
            int r = m * 16 + ll;
            af[m] = *(const bf16x8*)&sA[r][(((p * 4 + lg) ^ (r & 7)) << 3)];
        }
        #pragma unroll
        for (int m = 0; m < 4; ++m)
            #pragma unroll
            for (int nf = 0; nf < 2; ++nf)
                acc[m][nf] = __builtin_amdgcn_mfma_f32_16x16x32_bf16(
                    wbuf[p & 1][nf], af[m], acc[m][nf], 0, 0, 0);
    }
    __syncthreads();   // all waves done reading sA(U)

    // ---- t = silu(acc + b1) -> sA via ds_write_b64; reset acc
    #pragma unroll
    for (int m = 0; m < 4; ++m) {
        int r = m * 16 + ll, rx = r & 7;
        #pragma unroll
        for (int nf = 0; nf < 2; ++nf) {
            int chunk = ((cb + nf * 16) >> 3) + (lg >> 1);
            int celloff = ((chunk ^ rx) << 3) + (lg & 1) * 4;
            ushort4 o;
            o.x = f2bf(silu_f(acc[m][nf][0] + bv1v[nf][0]));
            o.y = f2bf(silu_f(acc[m][nf][1] + bv1v[nf][1]));
            o.z = f2bf(silu_f(acc[m][nf][2] + bv1v[nf][2]));
            o.w = f2bf(silu_f(acc[m][nf][3] + bv1v[nf][3]));
            *(ushort4*)&sA[r][celloff] = o;
            acc[m][nf][0] = 0.f; acc[m][nf][1] = 0.f;
            acc[m][nf][2] = 0.f; acc[m][nf][3] = 0.f;
        }
    }
    __syncthreads();   // t visible

    // ---- GEMM2
    #pragma unroll
    for (int p = 0; p < 8; ++p) {
        if (p < 7) {
            wbuf[(p + 1) & 1][0] = *(const bf16x8*)(wp2 + (p + 1) * 8192);
            wbuf[(p + 1) & 1][1] = *(const bf16x8*)(wp2 + (p + 1) * 8192 + 512);
        }
        bf16x8 af[4];
        #pragma unroll
        for (int m = 0; m < 4; ++m) {
            int r = m * 16 + ll;
            af[m] = *(const bf16x8*)&sA[r][(((p * 4 + lg) ^ (r & 7)) << 3)];
        }
        #pragma unroll
        for (int m = 0; m < 4; ++m)
            #pragma unroll
            for (int nf = 0; nf < 2; ++nf)
                acc[m][nf] = __builtin_amdgcn_mfma_f32_16x16x32_bf16(
                    wbuf[p & 1][nf], af[m], acc[m][nf], 0, 0, 0);
    }
    __syncthreads();   // all waves done reading sA(t)

    // ---- h = acc + b2 -> sA cells (ds_write_b64)
    #pragma unroll
    for (int m = 0; m < 4; ++m) {
        int r = m * 16 + ll, rx = r & 7;
        #pragma unroll
        for (int nf = 0; nf < 2; ++nf) {
            int chunk = ((cb + nf * 16) >> 3) + (lg >> 1);
            int celloff = ((chunk ^ rx) << 3) + (lg & 1) * 4;
            ushort4 o;
            o.x = f2bf(acc[m][nf][0] + bv2v[nf][0]);
            o.y = f2bf(acc[m][nf][1] + bv2v[nf][1]);
            o.z = f2bf(acc[m][nf][2] + bv2v[nf][2]);
            o.w = f2bf(acc[m][nf][3] + bv2v[nf][3]);
            *(ushort4*)&sA[r][celloff] = o;
        }
    }
    __syncthreads();   // h visible

    // ---- row-pass LN: 8 thr/row, rotation swizzle; x residual from global (L2/L3-hot)
    {
        int rr = tid >> 3, kk = tid & 7;
        int rot = (kk + rr) & 7;
        size_t rowb = ((size_t)(m0 + rr)) << 8;
        float s = 0.f, q = 0.f;
        #pragma unroll
        for (int i = 0; i < 4; ++i) {
            int slot = rot + 8 * i;
            u16x8 h8 = *(const u16x8*)&sA[rr][slot << 3];
            u16x8 x8 = *(const u16x8*)&xin[rowb + (slot << 3)];
            u16x8 v8;
            #pragma unroll
            for (int j = 0; j < 8; ++j) {
                float v = bf2f(h8[j]) + bf2f(x8[j]);
                s += v; q += v * v;
                v8[j] = f2bf(v);
            }
            *(u16x8*)&sA[rr][slot << 3] = v8;   // own cells; no cross-thread hazard
        }
        #pragma unroll
        for (int o = 1; o < 8; o <<= 1) {
            s += __shfl_xor(s, o, 64);
            q += __shfl_xor(q, o, 64);
        }
        float mu = s * (1.0f / HDIM);
        float var = q * (1.0f / HDIM) - mu * mu;
        float rs = rsqrtf(var + 1e-5f);
        #pragma unroll
        for (int i = 0; i < 4; ++i) {
            int slot = rot + 8 * i;
            int chunk = slot ^ (rr & 7);        // true cols chunk*8..+7
            u16x8 v8 = *(const u16x8*)&sA[rr][slot << 3];
            if (LAST) {
                float* xrow = xf32 + (((size_t)(m0 + rr)) << 8);
                f32x4 o0, o1;
                #pragma unroll
                for (int j = 0; j < 4; ++j) {
                    o0[j] = (bf2f(v8[j]) - mu) * rs * sGB[0][chunk * 8 + j]
                            + sGB[1][chunk * 8 + j];
                    o1[j] = (bf2f(v8[4 + j]) - mu) * rs * sGB[0][chunk * 8 + 4 + j]
                            + sGB[1][chunk * 8 + 4 + j];
                }
                *(f32x4*)&xrow[chunk * 8] = o0;
                *(f32x4*)&xrow[chunk * 8 + 4] = o1;
            } else {
                u16x8 o8;
                #pragma unroll
                for (int j = 0; j < 8; ++j)
                    o8[j] = f2bf((bf2f(v8[j]) - mu) * rs * sGB[0][chunk * 8 + j]
                                 + sGB[1][chunk * 8 + j]);
                *(u16x8*)&xout[rowb + (slot << 3)] = o8;
            }
        }
    }
}

extern "C" void kernel_launch(void* const* d_in, const int* in_sizes, int n_in,
                              void* d_out, int out_size, void* d_ws, size_t ws_size,
                              hipStream_t stream)
{
    const int*   z    = (const int*)d_in[0];
    const float* feat = (const float*)d_in[1];
    const int*   ei   = (const int*)d_in[2];
    const float* ea   = (const float*)d_in[3];
    const int*   batch= (const int*)d_in[4];
    const float* emb  = (const float*)d_in[5];
    const float* Wf   = (const float*)d_in[6];
    const float* bfv  = (const float*)d_in[7];
    const float* g0   = (const float*)d_in[8];
    const float* b0   = (const float*)d_in[9];
    const float* We   = (const float*)d_in[10];
    const float* be   = (const float*)d_in[11];
    const float* W1   = (const float*)d_in[12];
    const float* b1   = (const float*)d_in[13];
    const float* W2   = (const float*)d_in[14];
    const float* b2   = (const float*)d_in[15];
    const float* lng  = (const float*)d_in[16];
    const float* lnb  = (const float*)d_in[17];

    float* x    = (float*)d_out;
    float* outb = (float*)d_out + (size_t)NN * HDIM;

    char* ws = (char*)d_ws;
    ushort_t* xb0  = (ushort_t*)ws;                         // 102,400,000 B
    ushort_t* xb1  = (ushort_t*)(ws + 102400000);           // 102,400,000 B
    float4*   eaf  = (float4*)(ws + 204800000);             // 6,400,000 B
    int*      srcs = (int*)(ws + 211200000);                // 1,600,000 B
    int*      off  = (int*)(ws + 212800000);                // 800,016 B
    int*      cursor = (int*)(ws + 213600016);              // 800,000 B
    int*      deg  = (int*)(ws + 214400016);                // 800,000 B
    int*      psum = (int*)(ws + 215200016);                // 1,008 B
    ushort_t* Wc1  = (ushort_t*)(ws + 215201024);           // 524,288 B
    ushort_t* Wc2  = (ushort_t*)(ws + 215725312);           // 524,288 B
    void*     eprec= (void*)(ws + 216249600);               // fp8: 102.4MB / bf16: 204.8MB
#if HAVE_FP8
    const size_t eneed = (size_t)216249600 + (size_t)EE * 256;
#else
    const size_t eneed = (size_t)216249600 + (size_t)EE * 512;
#endif
    const int use_e = (ws_size >= eneed) ? 1 : 0;

    prep_w_kernel<<<2048, 256, 0, stream>>>(W1, W2, Wc1, Wc2);
    batch_out_kernel<<<782, 256, 0, stream>>>(batch, outb);
    node_init_kernel<<<NN / 8, 256, 0, stream>>>(z, feat, emb, Wf, bfv, g0, b0, xb0);

    hipMemsetAsync(deg, 0, NN * sizeof(int), stream);
    hist_kernel<<<1563, 256, 0, stream>>>(ei, deg);
    scan_blocks_kernel<<<196, 256, 0, stream>>>(deg, off, psum);
    scan_top_kernel<<<1, 256, 0, stream>>>(psum, 196);
    scan_add_kernel<<<782, 256, 0, stream>>>(off, psum, cursor);
    scatter_kernel<<<1563, 256, 0, stream>>>(ei, ea, cursor, srcs, eaf);
    if (use_e)
        edge_mlp_kernel<<<EE / 8, 256, 0, stream>>>(eaf, We, be, eprec);

    // ping-pong: layer l reads x=buf[l&1]; agg writes U into buf[(l+1)&1];
    // mlp writes its output IN PLACE over U (blocks touch only their own rows).
    ushort_t* xbuf[2] = {xb0, xb1};
    for (int l = 0; l < LL; ++l) {
        ushort_t* xin = xbuf[l & 1];
        ushort_t* Ub  = xbuf[(l + 1) & 1];
        if (use_e)
            agg_kernel<1><<<4096, 256, 0, stream>>>(off, srcs, eprec, eaf, We, be, xin, Ub);
        else
            agg_kernel<0><<<4096, 256, 0, stream>>>(off, srcs, eprec, eaf, We, be, xin, Ub);
        if (l == LL - 1) {
            mlp_kernel<1><<<NN / 64, 512, 0, stream>>>(
                Ub, Wc1 + l * 65536, Wc2 + l * 65536, b1 + l * HDIM, b2 + l * HDIM,
                lng + l * HDIM, lnb + l * HDIM, xin, Ub, x);
        } else {
            mlp_kernel<0><<<NN / 64, 512, 0, stream>>>(
                Ub, Wc1 + l * 65536, Wc2 + l * 65536, b1 + l * HDIM, b2 + l * HDIM,
                lng + l * HDIM, lnb + l * HDIM, xin, Ub, nullptr);
        }
    }
}

// Round 14
// 963.349 us; speedup vs baseline: 1.1365x; 1.1365x over previous
//
#include <hip/hip_runtime.h>
#include <hip/hip_bf16.h>

#define NN 200000
#define EE 400000
#define HDIM 256
#define LL 4
#define FEAT 10

#if defined(__has_builtin)
#if __has_builtin(__builtin_amdgcn_cvt_pk_fp8_f32) && __has_builtin(__builtin_amdgcn_cvt_pk_f32_fp8)
#define HAVE_FP8 1
#endif
#endif
#ifndef HAVE_FP8
#define HAVE_FP8 0
#endif

typedef unsigned short ushort_t;
typedef __attribute__((ext_vector_type(8))) short bf16x8;
typedef __attribute__((ext_vector_type(8))) unsigned short u16x8;
typedef __attribute__((ext_vector_type(2))) float f32x2;
typedef __attribute__((ext_vector_type(4))) float f32x4;
typedef __attribute__((ext_vector_type(4))) unsigned int u32x4;

__device__ inline ushort_t f2bf(float f) {
    unsigned int u = __builtin_bit_cast(unsigned int, f);
    return (ushort_t)((u + 0x7fffu + ((u >> 16) & 1u)) >> 16);
}
__device__ inline float bf2f(ushort_t s) {
    unsigned int u = ((unsigned int)s) << 16;
    return __builtin_bit_cast(float, u);
}
__device__ inline float silu_f(float v) { return v / (1.0f + __expf(-v)); }

// x/U global layout PRE-SWIZZLED: row n, 16B-chunk slot s holds true chunk s ^ (n&7).

// ---------------- Wf pre-pack: A-operand fragment layout, single K=32 chunk (k>=10 -> 0)
// Wfc[w<8][nf<2][lane<64][e<8] = (k<10) ? Wf[k][n] : 0,  k=(lane>>4)*8+e, n=w*32+nf*16+(lane&15)
__global__ __launch_bounds__(256) void prep_wf_kernel(
    const float* __restrict__ Wf, ushort_t* __restrict__ Wfc)
{
    int idx = blockIdx.x * 256 + threadIdx.x;   // 8192
    if (idx >= 8192) return;
    int e = idx & 7;
    int lane = (idx >> 3) & 63;
    int nf = (idx >> 9) & 1;
    int w8 = idx >> 10;
    int n = w8 * 32 + nf * 16 + (lane & 15);
    int k = (lane >> 4) * 8 + e;
    Wfc[idx] = (k < FEAT) ? f2bf(Wf[k * HDIM + n]) : (ushort_t)0;
}

// ---------------- node init via MFMA: xb = LN(silu(emb[z] + feat@Wf + bf))
// identical geometry/fragments to mlp_kernel's GEMM (single K-chunk), then row-pass LN
__global__ __launch_bounds__(512, 4) void node_init_kernel(
    const int* __restrict__ z, const float* __restrict__ feat,
    const float* __restrict__ emb, const ushort_t* __restrict__ Wfc,
    const float* __restrict__ bfv, const float* __restrict__ g0,
    const float* __restrict__ b0, ushort_t* __restrict__ xb)
{
    __shared__ ushort_t sA[64][256];
    __shared__ float sGB[2][HDIM];
    const int tid = threadIdx.x;
    const int m0 = blockIdx.x * 64;
    const int lane = tid & 63;
    const int w = tid >> 6;
    const int lg = lane >> 4, ll = lane & 15;
    const int cb = w * 32;

    if (tid < HDIM) sGB[0][tid] = g0[tid];
    else sGB[1][tid - HDIM] = b0[tid - HDIM];

    f32x4 bvv[2];
    #pragma unroll
    for (int nf = 0; nf < 2; ++nf)
        bvv[nf] = *(const f32x4*)&bfv[cb + nf * 16 + lg * 4];

    // weight fragments (A operand)
    bf16x8 wf[2];
    wf[0] = *(const bf16x8*)(Wfc + w * 1024 + lane * 8);
    wf[1] = *(const bf16x8*)(Wfc + w * 1024 + 512 + lane * 8);

    // feat fragments (B operand): af[m][e] = feat[row][lg*8+e], 0 beyond k=9
    bf16x8 af[4];
    #pragma unroll
    for (int m = 0; m < 4; ++m) {
        int gr = m0 + m * 16 + ll;
        bf16x8 t = {};
        if (lg == 0) {
            #pragma unroll
            for (int j = 0; j < 8; ++j) t[j] = (short)f2bf(feat[gr * FEAT + j]);
        } else if (lg == 1) {
            t[0] = (short)f2bf(feat[gr * FEAT + 8]);
            t[1] = (short)f2bf(feat[gr * FEAT + 9]);
        }
        af[m] = t;
    }

    f32x4 acc[4][2] = {};
    #pragma unroll
    for (int m = 0; m < 4; ++m)
        #pragma unroll
        for (int nf = 0; nf < 2; ++nf)
            acc[m][nf] = __builtin_amdgcn_mfma_f32_16x16x32_bf16(
                wf[nf], af[m], acc[m][nf], 0, 0, 0);

    // h = silu(acc + emb[z] + bf) -> sA cells (ds_write_b64; same cell math as mlp)
    #pragma unroll
    for (int m = 0; m < 4; ++m) {
        int r = m * 16 + ll, rx = r & 7;
        int zi = z[m0 + r];
        #pragma unroll
        for (int nf = 0; nf < 2; ++nf) {
            int n0 = cb + nf * 16 + lg * 4;
            f32x4 ev = *(const f32x4*)&emb[(size_t)zi * HDIM + n0];
            int chunk = ((cb + nf * 16) >> 3) + (lg >> 1);
            int celloff = ((chunk ^ rx) << 3) + (lg & 1) * 4;
            ushort4 o;
            o.x = f2bf(silu_f(acc[m][nf][0] + ev[0] + bvv[nf][0]));
            o.y = f2bf(silu_f(acc[m][nf][1] + ev[1] + bvv[nf][1]));
            o.z = f2bf(silu_f(acc[m][nf][2] + ev[2] + bvv[nf][2]));
            o.w = f2bf(silu_f(acc[m][nf][3] + ev[3] + bvv[nf][3]));
            *(ushort4*)&sA[r][celloff] = o;
        }
    }
    __syncthreads();

    // row-pass LN: 8 thr/row, rotation swizzle; write pre-swizzled global
    {
        int rr = tid >> 3, kk = tid & 7;
        int rot = (kk + rr) & 7;
        size_t rowb = ((size_t)(m0 + rr)) << 8;
        u16x8 v8[4];
        float s = 0.f, q = 0.f;
        #pragma unroll
        for (int i = 0; i < 4; ++i) {
            int slot = rot + 8 * i;
            v8[i] = *(const u16x8*)&sA[rr][slot << 3];
            #pragma unroll
            for (int j = 0; j < 8; ++j) {
                float v = bf2f(v8[i][j]);
                s += v; q += v * v;
            }
        }
        #pragma unroll
        for (int o = 1; o < 8; o <<= 1) {
            s += __shfl_xor(s, o, 64);
            q += __shfl_xor(q, o, 64);
        }
        float mu = s * (1.0f / HDIM);
        float var = q * (1.0f / HDIM) - mu * mu;
        float rs = rsqrtf(var + 1e-5f);
        #pragma unroll
        for (int i = 0; i < 4; ++i) {
            int slot = rot + 8 * i;
            int chunk = slot ^ (rr & 7);
            u16x8 o8;
            #pragma unroll
            for (int j = 0; j < 8; ++j)
                o8[j] = f2bf((bf2f(v8[i][j]) - mu) * rs * sGB[0][chunk * 8 + j]
                             + sGB[1][chunk * 8 + j]);
            *(u16x8*)&xb[rowb + (slot << 3)] = o8;
        }
    }
}

__global__ __launch_bounds__(256) void batch_out_kernel(
    const int* __restrict__ batch, float* __restrict__ out)
{
    int i = blockIdx.x * 256 + threadIdx.x;
    if (i < NN) out[i] = (float)batch[i];
}

// ---------------- CSR build
__global__ __launch_bounds__(256) void hist_kernel(const int* __restrict__ ei, int* __restrict__ deg)
{
    int i = blockIdx.x * 256 + threadIdx.x;
    if (i < EE) atomicAdd(&deg[ei[EE + i]], 1);
}

__global__ __launch_bounds__(256) void scan_blocks_kernel(
    const int* __restrict__ deg, int* __restrict__ off, int* __restrict__ psum)
{
    int blk = blockIdx.x, t = threadIdx.x;
    int base = blk * 1024 + t * 4;
    int v[4];
    #pragma unroll
    for (int i = 0; i < 4; ++i) v[i] = (base + i < NN) ? deg[base + i] : 0;
    int s = v[0] + v[1] + v[2] + v[3];
    int lane = t & 63, w = t >> 6;
    int ps = s;
    #pragma unroll
    for (int o = 1; o < 64; o <<= 1) { int u = __shfl_up(ps, o, 64); if (lane >= o) ps += u; }
    __shared__ int wt[4];
    if (lane == 63) wt[w] = ps;
    __syncthreads();
    int wbase = 0;
    for (int k = 0; k < w; ++k) wbase += wt[k];
    int run = wbase + ps - s;
    #pragma unroll
    for (int i = 0; i < 4; ++i) {
        if (base + i < NN) off[base + i] = run;
        run += v[i];
    }
    if (t == 255) psum[blk] = wbase + ps;
}

__global__ __launch_bounds__(256) void scan_top_kernel(int* __restrict__ psum, int nb)
{
    int t = threadIdx.x;
    int v = (t < nb) ? psum[t] : 0;
    int lane = t & 63, w = t >> 6;
    int ps = v;
    #pragma unroll
    for (int o = 1; o < 64; o <<= 1) { int u = __shfl_up(ps, o, 64); if (lane >= o) ps += u; }
    __shared__ int wt[4];
    if (lane == 63) wt[w] = ps;
    __syncthreads();
    int wbase = 0;
    for (int k = 0; k < w; ++k) wbase += wt[k];
    if (t < nb) psum[t] = wbase + ps - v;
}

__global__ __launch_bounds__(256) void scan_add_kernel(
    int* __restrict__ off, const int* __restrict__ psum, int* __restrict__ cursor)
{
    int i = blockIdx.x * 256 + threadIdx.x;
    if (i < NN) {
        int o = off[i] + psum[i >> 10];
        off[i] = o;
        cursor[i] = o;
        if (i == NN - 1) off[NN] = EE;
    }
}

__global__ __launch_bounds__(256) void scatter_kernel(
    const int* __restrict__ ei, const float* __restrict__ ea,
    int* __restrict__ cursor, int* __restrict__ srcs, float4* __restrict__ eaf)
{
    int i = blockIdx.x * 256 + threadIdx.x;
    if (i < EE) {
        int dst = ei[EE + i];
        int pos = atomicAdd(&cursor[dst], 1);
        srcs[pos] = ei[i];
        eaf[pos] = ((const float4*)ea)[i];
    }
}

// ---------------- edge MLP (layer-invariant): e = silu(eaf@We + be), CSR order.
__global__ __launch_bounds__(256) void edge_mlp_kernel(
    const float4* __restrict__ eaf, const float* __restrict__ We,
    const float* __restrict__ be, void* __restrict__ eout)
{
    int p = (blockIdx.x * 256 + threadIdx.x) >> 5;
    if (p >= EE) return;
    int nl = threadIdx.x & 31, c0 = nl * 8;
    float4 av = eaf[p];
    float v[8];
    #pragma unroll
    for (int j = 0; j < 8; ++j) {
        float t = be[c0 + j] + av.x * We[c0 + j] + av.y * We[HDIM + c0 + j]
                + av.z * We[2 * HDIM + c0 + j] + av.w * We[3 * HDIM + c0 + j];
        v[j] = silu_f(t);
    }
#if HAVE_FP8
    int t0 = __builtin_amdgcn_cvt_pk_fp8_f32(v[0], v[1], 0, false);
    t0 = __builtin_amdgcn_cvt_pk_fp8_f32(v[2], v[3], t0, true);
    int t1 = __builtin_amdgcn_cvt_pk_fp8_f32(v[4], v[5], 0, false);
    t1 = __builtin_amdgcn_cvt_pk_fp8_f32(v[6], v[7], t1, true);
    uint2 o;
    o.x = (unsigned int)t0;
    o.y = (unsigned int)t1;
    ((uint2*)eout)[(size_t)p * 32 + nl] = o;
#else
    u16x8 o8;
    #pragma unroll
    for (int j = 0; j < 8; ++j) o8[j] = f2bf(v[j]);
    *(u16x8*)&((ushort_t*)eout)[((size_t)p << 8) + nl * 8] = o8;
#endif
}

// ---------------- weights: W[l][k][n] f32 -> chunk-major per-wave (8 col-waves) bf16
__global__ __launch_bounds__(256) void prep_w_kernel(
    const float* __restrict__ W1, const float* __restrict__ W2,
    ushort_t* __restrict__ Wc1, ushort_t* __restrict__ Wc2)
{
    int idx = blockIdx.x * 256 + threadIdx.x;   // 2 * 4 * 65536
    int which = idx >> 18;
    int rem = idx & 0x3FFFF;
    int l = rem >> 16;
    int t = rem & 0xFFFF;
    int e = t & 7;
    int lane = (t >> 3) & 63;
    int nf = (t >> 9) & 1;
    int w8 = (t >> 10) & 7;
    int c = (t >> 13) & 7;
    int n = w8 * 32 + nf * 16 + (lane & 15);
    int k = c * 32 + (lane >> 4) * 8 + e;
    const float* W = which ? W2 : W1;
    ushort_t* Wc = which ? Wc2 : Wc1;
    Wc[rem] = f2bf(W[l * 65536 + k * 256 + n]);
}

// ---------------- aggregation: U = bf16(x_self + sum relu(x[src]+e)); 32-lane groups
template<int USE_E>
__global__ __launch_bounds__(256) void agg_kernel(
    const int* __restrict__ off, const int* __restrict__ srcs,
    const void* __restrict__ eprec, const float4* __restrict__ eaf,
    const float* __restrict__ We, const float* __restrict__ be,
    const ushort_t* __restrict__ xin, ushort_t* __restrict__ U)
{
    const int gstride = (gridDim.x * 256) >> 5;
    const int gid0 = (blockIdx.x * 256 + threadIdx.x) >> 5;
    const int nl = threadIdx.x & 31, c0 = nl * 8;
    float wv[4][8], bev[8];
    if (!USE_E) {
        #pragma unroll
        for (int r4 = 0; r4 < 4; ++r4)
            #pragma unroll
            for (int j = 0; j < 8; ++j) wv[r4][j] = We[r4 * HDIM + c0 + j];
        #pragma unroll
        for (int j = 0; j < 8; ++j) bev[j] = be[c0 + j];
    }

    for (int n = gid0; n < NN; n += gstride) {
        u16x8 xs = *(const u16x8*)&xin[((size_t)n << 8) + ((nl ^ (n & 7)) << 3)];
        float acc[8];
        #pragma unroll
        for (int j = 0; j < 8; ++j) acc[j] = bf2f(xs[j]);
        int beg = off[n], end = off[n + 1];
        if (USE_E) {
            for (int p = beg; p < end; ++p) {
                int src = srcs[p];
                u16x8 xg = *(const u16x8*)&xin[((size_t)src << 8) + ((nl ^ (src & 7)) << 3)];
#if HAVE_FP8
                uint2 eg = ((const uint2*)eprec)[(size_t)p * 32 + nl];
                f32x2 e01 = __builtin_amdgcn_cvt_pk_f32_fp8((int)eg.x, false);
                f32x2 e23 = __builtin_amdgcn_cvt_pk_f32_fp8((int)eg.x, true);
                f32x2 e45 = __builtin_amdgcn_cvt_pk_f32_fp8((int)eg.y, false);
                f32x2 e67 = __builtin_amdgcn_cvt_pk_f32_fp8((int)eg.y, true);
                float ev[8] = {e01[0], e01[1], e23[0], e23[1],
                               e45[0], e45[1], e67[0], e67[1]};
#else
                u16x8 eg = *(const u16x8*)&((const ushort_t*)eprec)[((size_t)p << 8) + nl * 8];
                float ev[8];
                #pragma unroll
                for (int j = 0; j < 8; ++j) ev[j] = bf2f(eg[j]);
#endif
                #pragma unroll
                for (int j = 0; j < 8; ++j)
                    acc[j] += fmaxf(bf2f(xg[j]) + ev[j], 0.f);
            }
        } else {
            for (int p = beg; p < end; ++p) {
                int src = srcs[p];
                float4 av = eaf[p];
                u16x8 xg = *(const u16x8*)&xin[((size_t)src << 8) + ((nl ^ (src & 7)) << 3)];
                #pragma unroll
                for (int j = 0; j < 8; ++j) {
                    float e = silu_f(bev[j] + av.x * wv[0][j] + av.y * wv[1][j]
                                            + av.z * wv[2][j] + av.w * wv[3][j]);
                    acc[j] += fmaxf(bf2f(xg[j]) + e, 0.f);
                }
            }
        }
        u16x8 o8;
        #pragma unroll
        for (int j = 0; j < 8; ++j) o8[j] = f2bf(acc[j]);
        *(u16x8*)&U[((size_t)n << 8) + ((nl ^ (n & 7)) << 3)] = o8;
    }
}

// ---------------- MLP + LN (r12 exact): out = LN(xin + (silu(U@W1+b1))@W2 + b2)
template<int LAST>
__global__ __launch_bounds__(512, 4) void mlp_kernel(
    const ushort_t* U, const ushort_t* __restrict__ Wc1,
    const ushort_t* __restrict__ Wc2, const float* __restrict__ b1,
    const float* __restrict__ b2, const float* __restrict__ lng,
    const float* __restrict__ lnb, const ushort_t* __restrict__ xin,
    ushort_t* xout, float* __restrict__ xf32)
{
    __shared__ ushort_t sA[64][256];     // 32KB: U -> t -> h/v (swizzled cells)
    __shared__ float sGB[2][HDIM];       // 2KB gamma/beta
    const int tid = threadIdx.x;
    const int m0 = blockIdx.x * 64;
    const int lane = tid & 63;
    const int w = tid >> 6;
    const int lg = lane >> 4, ll = lane & 15;
    const int cb = w * 32;

    if (tid < HDIM) sGB[0][tid] = lng[tid];
    else sGB[1][tid - HDIM] = lnb[tid - HDIM];

    f32x4 bv1v[2], bv2v[2];
    #pragma unroll
    for (int nf = 0; nf < 2; ++nf) {
        int nb = cb + nf * 16 + lg * 4;
        bv1v[nf] = *(const f32x4*)&b1[nb];
        bv2v[nf] = *(const f32x4*)&b2[nb];
    }

    // ---- stage U tile (linear; global pre-swizzled)
    #pragma unroll
    for (int it = 0; it < 4; ++it) {
        int idx = tid + it * 512;
        *(u32x4*)((ushort_t*)sA + (idx << 3)) =
            *(const u32x4*)(U + (((size_t)m0) << 8) + (idx << 3));
    }
    __syncthreads();

    f32x4 acc[4][2] = {};
    const ushort_t* wp1 = Wc1 + w * 1024 + lane * 8;
    const ushort_t* wp2 = Wc2 + w * 1024 + lane * 8;
    bf16x8 wbuf[2][2];
    wbuf[0][0] = *(const bf16x8*)(wp1);
    wbuf[0][1] = *(const bf16x8*)(wp1 + 512);

    // ---- GEMM1 (reg prefetch; last iter prefetches W2 chunk0); W as A-operand
    #pragma unroll
    for (int p = 0; p < 8; ++p) {
        const ushort_t* nsrc = (p < 7) ? (wp1 + (p + 1) * 8192) : wp2;
        wbuf[(p + 1) & 1][0] = *(const bf16x8*)(nsrc);
        wbuf[(p + 1) & 1][1] = *(const bf16x8*)(nsrc + 512);
        bf16x8 af[4];
        #pragma unroll
        for (int m = 0; m < 4; ++m) {
            int r = m * 16 + ll;
            af[m] = *(const bf16x8*)&sA[r][(((p * 4 + lg) ^ (r & 7)) << 3)];
        }
        #pragma unroll
        for (int m = 0; m < 4; ++m)
            #pragma unroll
            for (int nf = 0; nf < 2; ++nf)
                acc[m][nf] = __builtin_amdgcn_mfma_f32_16x16x32_bf16(
                    wbuf[p & 1][nf], af[m], acc[m][nf], 0, 0, 0);
    }
    __syncthreads();   // all waves done reading sA(U)

    // ---- t = silu(acc + b1) -> sA via ds_write_b64; reset acc
    #pragma unroll
    for (int m = 0; m < 4; ++m) {
        int r = m * 16 + ll, rx = r & 7;
        #pragma unroll
        for (int nf = 0; nf < 2; ++nf) {
            int chunk = ((cb + nf * 16) >> 3) + (lg >> 1);
            int celloff = ((chunk ^ rx) << 3) + (lg & 1) * 4;
            ushort4 o;
            o.x = f2bf(silu_f(acc[m][nf][0] + bv1v[nf][0]));
            o.y = f2bf(silu_f(acc[m][nf][1] + bv1v[nf][1]));
            o.z = f2bf(silu_f(acc[m][nf][2] + bv1v[nf][2]));
            o.w = f2bf(silu_f(acc[m][nf][3] + bv1v[nf][3]));
            *(ushort4*)&sA[r][celloff] = o;
            acc[m][nf][0] = 0.f; acc[m][nf][1] = 0.f;
            acc[m][nf][2] = 0.f; acc[m][nf][3] = 0.f;
        }
    }
    __syncthreads();   // t visible

    // ---- GEMM2
    #pragma unroll
    for (int p = 0; p < 8; ++p) {
        if (p < 7) {
            wbuf[(p + 1) & 1][0] = *(const bf16x8*)(wp2 + (p + 1) * 8192);
            wbuf[(p + 1) & 1][1] = *(const bf16x8*)(wp2 + (p + 1) * 8192 + 512);
        }
        bf16x8 af[4];
        #pragma unroll
        for (int m = 0; m < 4; ++m) {
            int r = m * 16 + ll;
            af[m] = *(const bf16x8*)&sA[r][(((p * 4 + lg) ^ (r & 7)) << 3)];
        }
        #pragma unroll
        for (int m = 0; m < 4; ++m)
            #pragma unroll
            for (int nf = 0; nf < 2; ++nf)
                acc[m][nf] = __builtin_amdgcn_mfma_f32_16x16x32_bf16(
                    wbuf[p & 1][nf], af[m], acc[m][nf], 0, 0, 0);
    }
    __syncthreads();   // all waves done reading sA(t)

    // ---- h = acc + b2 -> sA cells (ds_write_b64)
    #pragma unroll
    for (int m = 0; m < 4; ++m) {
        int r = m * 16 + ll, rx = r & 7;
        #pragma unroll
        for (int nf = 0; nf < 2; ++nf) {
            int chunk = ((cb + nf * 16) >> 3) + (lg >> 1);
            int celloff = ((chunk ^ rx) << 3) + (lg & 1) * 4;
            ushort4 o;
            o.x = f2bf(acc[m][nf][0] + bv2v[nf][0]);
            o.y = f2bf(acc[m][nf][1] + bv2v[nf][1]);
            o.z = f2bf(acc[m][nf][2] + bv2v[nf][2]);
            o.w = f2bf(acc[m][nf][3] + bv2v[nf][3]);
            *(ushort4*)&sA[r][celloff] = o;
        }
    }
    __syncthreads();   // h visible

    // ---- row-pass LN: 8 thr/row, rotation swizzle; x residual from global
    {
        int rr = tid >> 3, kk = tid & 7;
        int rot = (kk + rr) & 7;
        size_t rowb = ((size_t)(m0 + rr)) << 8;
        float s = 0.f, q = 0.f;
        #pragma unroll
        for (int i = 0; i < 4; ++i) {
            int slot = rot + 8 * i;
            u16x8 h8 = *(const u16x8*)&sA[rr][slot << 3];
            u16x8 x8 = *(const u16x8*)&xin[rowb + (slot << 3)];
            u16x8 v8;
            #pragma unroll
            for (int j = 0; j < 8; ++j) {
                float v = bf2f(h8[j]) + bf2f(x8[j]);
                s += v; q += v * v;
                v8[j] = f2bf(v);
            }
            *(u16x8*)&sA[rr][slot << 3] = v8;
        }
        #pragma unroll
        for (int o = 1; o < 8; o <<= 1) {
            s += __shfl_xor(s, o, 64);
            q += __shfl_xor(q, o, 64);
        }
        float mu = s * (1.0f / HDIM);
        float var = q * (1.0f / HDIM) - mu * mu;
        float rs = rsqrtf(var + 1e-5f);
        #pragma unroll
        for (int i = 0; i < 4; ++i) {
            int slot = rot + 8 * i;
            int chunk = slot ^ (rr & 7);
            u16x8 v8 = *(const u16x8*)&sA[rr][slot << 3];
            if (LAST) {
                float* xrow = xf32 + (((size_t)(m0 + rr)) << 8);
                f32x4 o0, o1;
                #pragma unroll
                for (int j = 0; j < 4; ++j) {
                    o0[j] = (bf2f(v8[j]) - mu) * rs * sGB[0][chunk * 8 + j]
                            + sGB[1][chunk * 8 + j];
                    o1[j] = (bf2f(v8[4 + j]) - mu) * rs * sGB[0][chunk * 8 + 4 + j]
                            + sGB[1][chunk * 8 + 4 + j];
                }
                *(f32x4*)&xrow[chunk * 8] = o0;
                *(f32x4*)&xrow[chunk * 8 + 4] = o1;
            } else {
                u16x8 o8;
                #pragma unroll
                for (int j = 0; j < 8; ++j)
                    o8[j] = f2bf((bf2f(v8[j]) - mu) * rs * sGB[0][chunk * 8 + j]
                                 + sGB[1][chunk * 8 + j]);
                *(u16x8*)&xout[rowb + (slot << 3)] = o8;
            }
        }
    }
}

extern "C" void kernel_launch(void* const* d_in, const int* in_sizes, int n_in,
                              void* d_out, int out_size, void* d_ws, size_t ws_size,
                              hipStream_t stream)
{
    const int*   z    = (const int*)d_in[0];
    const float* feat = (const float*)d_in[1];
    const int*   ei   = (const int*)d_in[2];
    const float* ea   = (const float*)d_in[3];
    const int*   batch= (const int*)d_in[4];
    const float* emb  = (const float*)d_in[5];
    const float* Wf   = (const float*)d_in[6];
    const float* bfv  = (const float*)d_in[7];
    const float* g0   = (const float*)d_in[8];
    const float* b0   = (const float*)d_in[9];
    const float* We   = (const float*)d_in[10];
    const float* be   = (const float*)d_in[11];
    const float* W1   = (const float*)d_in[12];
    const float* b1   = (const float*)d_in[13];
    const float* W2   = (const float*)d_in[14];
    const float* b2   = (const float*)d_in[15];
    const float* lng  = (const float*)d_in[16];
    const float* lnb  = (const float*)d_in[17];

    float* x    = (float*)d_out;
    float* outb = (float*)d_out + (size_t)NN * HDIM;

    char* ws = (char*)d_ws;
    ushort_t* xb0  = (ushort_t*)ws;                         // 102,400,000 B
    ushort_t* xb1  = (ushort_t*)(ws + 102400000);           // 102,400,000 B
    float4*   eaf  = (float4*)(ws + 204800000);             // 6,400,000 B
    int*      srcs = (int*)(ws + 211200000);                // 1,600,000 B
    int*      off  = (int*)(ws + 212800000);                // 800,016 B
    int*      cursor = (int*)(ws + 213600016);              // 800,000 B
    int*      deg  = (int*)(ws + 214400016);                // 800,000 B
    int*      psum = (int*)(ws + 215200016);                // 1,008 B
    ushort_t* Wc1  = (ushort_t*)(ws + 215201024);           // 524,288 B
    ushort_t* Wc2  = (ushort_t*)(ws + 215725312);           // 524,288 B
    ushort_t* Wfc  = (ushort_t*)(ws + 216249600);           // 16,384 B
    void*     eprec= (void*)(ws + 216265984);               // fp8: 102.4MB / bf16: 204.8MB
#if HAVE_FP8
    const size_t eneed = (size_t)216265984 + (size_t)EE * 256;
#else
    const size_t eneed = (size_t)216265984 + (size_t)EE * 512;
#endif
    const int use_e = (ws_size >= eneed) ? 1 : 0;

    prep_w_kernel<<<2048, 256, 0, stream>>>(W1, W2, Wc1, Wc2);
    prep_wf_kernel<<<32, 256, 0, stream>>>(Wf, Wfc);
    batch_out_kernel<<<782, 256, 0, stream>>>(batch, outb);
    node_init_kernel<<<NN / 64, 512, 0, stream>>>(z, feat, emb, Wfc, bfv, g0, b0, xb0);

    hipMemsetAsync(deg, 0, NN * sizeof(int), stream);
    hist_kernel<<<1563, 256, 0, stream>>>(ei, deg);
    scan_blocks_kernel<<<196, 256, 0, stream>>>(deg, off, psum);
    scan_top_kernel<<<1, 256, 0, stream>>>(psum, 196);
    scan_add_kernel<<<782, 256, 0, stream>>>(off, psum, cursor);
    scatter_kernel<<<1563, 256, 0, stream>>>(ei, ea, cursor, srcs, eaf);
    if (use_e)
        edge_mlp_kernel<<<EE / 8, 256, 0, stream>>>(eaf, We, be, eprec);

    // ping-pong: layer l reads x=buf[l&1]; agg writes U into buf[(l+1)&1];
    // mlp writes its output IN PLACE over U (blocks touch only their own rows).
    ushort_t* xbuf[2] = {xb0, xb1};
    for (int l = 0; l < LL; ++l) {
        ushort_t* xin = xbuf[l & 1];
        ushort_t* Ub  = xbuf[(l + 1) & 1];
        if (use_e)
            agg_kernel<1><<<2048, 256, 0, stream>>>(off, srcs, eprec, eaf, We, be, xin, Ub);
        else
            agg_kernel<0><<<2048, 256, 0, stream>>>(off, srcs, eprec, eaf, We, be, xin, Ub);
        if (l == LL - 1) {
            mlp_kernel<1><<<NN / 64, 512, 0, stream>>>(
                Ub, Wc1 + l * 65536, Wc2 + l * 65536, b1 + l * HDIM, b2 + l * HDIM,
                lng + l * HDIM, lnb + l * HDIM, xin, Ub, x);
        } else {
            mlp_kernel<0><<<NN / 64, 512, 0, stream>>>(
                Ub, Wc1 + l * 65536, Wc2 + l * 65536, b1 + l * HDIM, b2 + l * HDIM,
                lng + l * HDIM, lnb + l * HDIM, xin, Ub, nullptr);
        }
    }
}

// Round 15
// 961.446 us; speedup vs baseline: 1.1388x; 1.0020x over previous
//
#include <hip/hip_runtime.h>
#include <hip/hip_bf16.h>

#define NN 200000
#define EE 400000
#define HDIM 256
#define LL 4
#define FEAT 10

#if defined(__has_builtin)
#if __has_builtin(__builtin_amdgcn_cvt_pk_fp8_f32) && __has_builtin(__builtin_amdgcn_cvt_pk_f32_fp8)
#define HAVE_FP8 1
#endif
#endif
#ifndef HAVE_FP8
#define HAVE_FP8 0
#endif

typedef unsigned short ushort_t;
typedef __attribute__((ext_vector_type(8))) short bf16x8;
typedef __attribute__((ext_vector_type(8))) unsigned short u16x8;
typedef __attribute__((ext_vector_type(2))) float f32x2;
typedef __attribute__((ext_vector_type(4))) float f32x4;
typedef __attribute__((ext_vector_type(4))) unsigned int u32x4;

__device__ inline ushort_t f2bf(float f) {
    unsigned int u = __builtin_bit_cast(unsigned int, f);
    return (ushort_t)((u + 0x7fffu + ((u >> 16) & 1u)) >> 16);
}
__device__ inline float bf2f(ushort_t s) {
    unsigned int u = ((unsigned int)s) << 16;
    return __builtin_bit_cast(float, u);
}
__device__ inline float silu_f(float v) { return v / (1.0f + __expf(-v)); }

// x/U global layout PRE-SWIZZLED: row n, 16B-chunk slot s holds true chunk s ^ (n&7).

// ---------------- Wf pre-pack: A-operand fragment layout, single K=32 chunk (k>=10 -> 0)
__global__ __launch_bounds__(256) void prep_wf_kernel(
    const float* __restrict__ Wf, ushort_t* __restrict__ Wfc)
{
    int idx = blockIdx.x * 256 + threadIdx.x;   // 8192
    if (idx >= 8192) return;
    int e = idx & 7;
    int lane = (idx >> 3) & 63;
    int nf = (idx >> 9) & 1;
    int w8 = idx >> 10;
    int n = w8 * 32 + nf * 16 + (lane & 15);
    int k = (lane >> 4) * 8 + e;
    Wfc[idx] = (k < FEAT) ? f2bf(Wf[k * HDIM + n]) : (ushort_t)0;
}

// ---------------- node init via MFMA: xb = LN(silu(emb[z] + feat@Wf + bf))
__global__ __launch_bounds__(512, 4) void node_init_kernel(
    const int* __restrict__ z, const float* __restrict__ feat,
    const float* __restrict__ emb, const ushort_t* __restrict__ Wfc,
    const float* __restrict__ bfv, const float* __restrict__ g0,
    const float* __restrict__ b0, ushort_t* __restrict__ xb)
{
    __shared__ ushort_t sA[64][256];
    __shared__ float sGB[2][HDIM];
    const int tid = threadIdx.x;
    const int m0 = blockIdx.x * 64;
    const int lane = tid & 63;
    const int w = tid >> 6;
    const int lg = lane >> 4, ll = lane & 15;
    const int cb = w * 32;

    if (tid < HDIM) sGB[0][tid] = g0[tid];
    else sGB[1][tid - HDIM] = b0[tid - HDIM];

    f32x4 bvv[2];
    #pragma unroll
    for (int nf = 0; nf < 2; ++nf)
        bvv[nf] = *(const f32x4*)&bfv[cb + nf * 16 + lg * 4];

    bf16x8 wf[2];
    wf[0] = *(const bf16x8*)(Wfc + w * 1024 + lane * 8);
    wf[1] = *(const bf16x8*)(Wfc + w * 1024 + 512 + lane * 8);

    bf16x8 af[4];
    #pragma unroll
    for (int m = 0; m < 4; ++m) {
        int gr = m0 + m * 16 + ll;
        bf16x8 t = {};
        if (lg == 0) {
            #pragma unroll
            for (int j = 0; j < 8; ++j) t[j] = (short)f2bf(feat[gr * FEAT + j]);
        } else if (lg == 1) {
            t[0] = (short)f2bf(feat[gr * FEAT + 8]);
            t[1] = (short)f2bf(feat[gr * FEAT + 9]);
        }
        af[m] = t;
    }

    f32x4 acc[4][2] = {};
    #pragma unroll
    for (int m = 0; m < 4; ++m)
        #pragma unroll
        for (int nf = 0; nf < 2; ++nf)
            acc[m][nf] = __builtin_amdgcn_mfma_f32_16x16x32_bf16(
                wf[nf], af[m], acc[m][nf], 0, 0, 0);

    #pragma unroll
    for (int m = 0; m < 4; ++m) {
        int r = m * 16 + ll, rx = r & 7;
        int zi = z[m0 + r];
        #pragma unroll
        for (int nf = 0; nf < 2; ++nf) {
            int n0 = cb + nf * 16 + lg * 4;
            f32x4 ev = *(const f32x4*)&emb[(size_t)zi * HDIM + n0];
            int chunk = ((cb + nf * 16) >> 3) + (lg >> 1);
            int celloff = ((chunk ^ rx) << 3) + (lg & 1) * 4;
            ushort4 o;
            o.x = f2bf(silu_f(acc[m][nf][0] + ev[0] + bvv[nf][0]));
            o.y = f2bf(silu_f(acc[m][nf][1] + ev[1] + bvv[nf][1]));
            o.z = f2bf(silu_f(acc[m][nf][2] + ev[2] + bvv[nf][2]));
            o.w = f2bf(silu_f(acc[m][nf][3] + ev[3] + bvv[nf][3]));
            *(ushort4*)&sA[r][celloff] = o;
        }
    }
    __syncthreads();

    {
        int rr = tid >> 3, kk = tid & 7;
        int rot = (kk + rr) & 7;
        size_t rowb = ((size_t)(m0 + rr)) << 8;
        u16x8 v8[4];
        float s = 0.f, q = 0.f;
        #pragma unroll
        for (int i = 0; i < 4; ++i) {
            int slot = rot + 8 * i;
            v8[i] = *(const u16x8*)&sA[rr][slot << 3];
            #pragma unroll
            for (int j = 0; j < 8; ++j) {
                float v = bf2f(v8[i][j]);
                s += v; q += v * v;
            }
        }
        #pragma unroll
        for (int o = 1; o < 8; o <<= 1) {
            s += __shfl_xor(s, o, 64);
            q += __shfl_xor(q, o, 64);
        }
        float mu = s * (1.0f / HDIM);
        float var = q * (1.0f / HDIM) - mu * mu;
        float rs = rsqrtf(var + 1e-5f);
        #pragma unroll
        for (int i = 0; i < 4; ++i) {
            int slot = rot + 8 * i;
            int chunk = slot ^ (rr & 7);
            u16x8 o8;
            #pragma unroll
            for (int j = 0; j < 8; ++j)
                o8[j] = f2bf((bf2f(v8[i][j]) - mu) * rs * sGB[0][chunk * 8 + j]
                             + sGB[1][chunk * 8 + j]);
            *(u16x8*)&xb[rowb + (slot << 3)] = o8;
        }
    }
}

__global__ __launch_bounds__(256) void batch_out_kernel(
    const int* __restrict__ batch, float* __restrict__ out)
{
    int i = blockIdx.x * 256 + threadIdx.x;
    if (i < NN) out[i] = (float)batch[i];
}

// ---------------- CSR build
__global__ __launch_bounds__(256) void hist_kernel(const int* __restrict__ ei, int* __restrict__ deg)
{
    int i = blockIdx.x * 256 + threadIdx.x;
    if (i < EE) atomicAdd(&deg[ei[EE + i]], 1);
}

__global__ __launch_bounds__(256) void scan_blocks_kernel(
    const int* __restrict__ deg, int* __restrict__ off, int* __restrict__ psum)
{
    int blk = blockIdx.x, t = threadIdx.x;
    int base = blk * 1024 + t * 4;
    int v[4];
    #pragma unroll
    for (int i = 0; i < 4; ++i) v[i] = (base + i < NN) ? deg[base + i] : 0;
    int s = v[0] + v[1] + v[2] + v[3];
    int lane = t & 63, w = t >> 6;
    int ps = s;
    #pragma unroll
    for (int o = 1; o < 64; o <<= 1) { int u = __shfl_up(ps, o, 64); if (lane >= o) ps += u; }
    __shared__ int wt[4];
    if (lane == 63) wt[w] = ps;
    __syncthreads();
    int wbase = 0;
    for (int k = 0; k < w; ++k) wbase += wt[k];
    int run = wbase + ps - s;
    #pragma unroll
    for (int i = 0; i < 4; ++i) {
        if (base + i < NN) off[base + i] = run;
        run += v[i];
    }
    if (t == 255) psum[blk] = wbase + ps;
}

__global__ __launch_bounds__(256) void scan_top_kernel(int* __restrict__ psum, int nb)
{
    int t = threadIdx.x;
    int v = (t < nb) ? psum[t] : 0;
    int lane = t & 63, w = t >> 6;
    int ps = v;
    #pragma unroll
    for (int o = 1; o < 64; o <<= 1) { int u = __shfl_up(ps, o, 64); if (lane >= o) ps += u; }
    __shared__ int wt[4];
    if (lane == 63) wt[w] = ps;
    __syncthreads();
    int wbase = 0;
    for (int k = 0; k < w; ++k) wbase += wt[k];
    if (t < nb) psum[t] = wbase + ps - v;
}

__global__ __launch_bounds__(256) void scan_add_kernel(
    int* __restrict__ off, const int* __restrict__ psum, int* __restrict__ cursor)
{
    int i = blockIdx.x * 256 + threadIdx.x;
    if (i < NN) {
        int o = off[i] + psum[i >> 10];
        off[i] = o;
        cursor[i] = o;
        if (i == NN - 1) off[NN] = EE;
    }
}

__global__ __launch_bounds__(256) void scatter_kernel(
    const int* __restrict__ ei, const float* __restrict__ ea,
    int* __restrict__ cursor, int* __restrict__ srcs, float4* __restrict__ eaf)
{
    int i = blockIdx.x * 256 + threadIdx.x;
    if (i < EE) {
        int dst = ei[EE + i];
        int pos = atomicAdd(&cursor[dst], 1);
        srcs[pos] = ei[i];
        eaf[pos] = ((const float4*)ea)[i];
    }
}

// ---------------- edge MLP (layer-invariant): e = silu(eaf@We + be), CSR order.
__global__ __launch_bounds__(256) void edge_mlp_kernel(
    const float4* __restrict__ eaf, const float* __restrict__ We,
    const float* __restrict__ be, void* __restrict__ eout)
{
    int p = (blockIdx.x * 256 + threadIdx.x) >> 5;
    if (p >= EE) return;
    int nl = threadIdx.x & 31, c0 = nl * 8;
    float4 av = eaf[p];
    float v[8];
    #pragma unroll
    for (int j = 0; j < 8; ++j) {
        float t = be[c0 + j] + av.x * We[c0 + j] + av.y * We[HDIM + c0 + j]
                + av.z * We[2 * HDIM + c0 + j] + av.w * We[3 * HDIM + c0 + j];
        v[j] = silu_f(t);
    }
#if HAVE_FP8
    int t0 = __builtin_amdgcn_cvt_pk_fp8_f32(v[0], v[1], 0, false);
    t0 = __builtin_amdgcn_cvt_pk_fp8_f32(v[2], v[3], t0, true);
    int t1 = __builtin_amdgcn_cvt_pk_fp8_f32(v[4], v[5], 0, false);
    t1 = __builtin_amdgcn_cvt_pk_fp8_f32(v[6], v[7], t1, true);
    uint2 o;
    o.x = (unsigned int)t0;
    o.y = (unsigned int)t1;
    ((uint2*)eout)[(size_t)p * 32 + nl] = o;
#else
    u16x8 o8;
    #pragma unroll
    for (int j = 0; j < 8; ++j) o8[j] = f2bf(v[j]);
    *(u16x8*)&((ushort_t*)eout)[((size_t)p << 8) + nl * 8] = o8;
#endif
}

// ---------------- weights: W[l][k][n] f32 -> chunk-major per-wave (8 col-waves) bf16
__global__ __launch_bounds__(256) void prep_w_kernel(
    const float* __restrict__ W1, const float* __restrict__ W2,
    ushort_t* __restrict__ Wc1, ushort_t* __restrict__ Wc2)
{
    int idx = blockIdx.x * 256 + threadIdx.x;   // 2 * 4 * 65536
    int which = idx >> 18;
    int rem = idx & 0x3FFFF;
    int l = rem >> 16;
    int t = rem & 0xFFFF;
    int e = t & 7;
    int lane = (t >> 3) & 63;
    int nf = (t >> 9) & 1;
    int w8 = (t >> 10) & 7;
    int c = (t >> 13) & 7;
    int n = w8 * 32 + nf * 16 + (lane & 15);
    int k = c * 32 + (lane >> 4) * 8 + e;
    const float* W = which ? W2 : W1;
    ushort_t* Wc = which ? Wc2 : Wc1;
    Wc[rem] = f2bf(W[l * 65536 + k * 256 + n]);
}

// ---------------- aggregation: U = bf16(x_self + sum relu(x[src]+e)); 32-lane groups
template<int USE_E>
__global__ __launch_bounds__(256) void agg_kernel(
    const int* __restrict__ off, const int* __restrict__ srcs,
    const void* __restrict__ eprec, const float4* __restrict__ eaf,
    const float* __restrict__ We, const float* __restrict__ be,
    const ushort_t* __restrict__ xin, ushort_t* __restrict__ U)
{
    const int gstride = (gridDim.x * 256) >> 5;
    const int gid0 = (blockIdx.x * 256 + threadIdx.x) >> 5;
    const int nl = threadIdx.x & 31, c0 = nl * 8;
    float wv[4][8], bev[8];
    if (!USE_E) {
        #pragma unroll
        for (int r4 = 0; r4 < 4; ++r4)
            #pragma unroll
            for (int j = 0; j < 8; ++j) wv[r4][j] = We[r4 * HDIM + c0 + j];
        #pragma unroll
        for (int j = 0; j < 8; ++j) bev[j] = be[c0 + j];
    }

    for (int n = gid0; n < NN; n += gstride) {
        u16x8 xs = *(const u16x8*)&xin[((size_t)n << 8) + ((nl ^ (n & 7)) << 3)];
        float acc[8];
        #pragma unroll
        for (int j = 0; j < 8; ++j) acc[j] = bf2f(xs[j]);
        int beg = off[n], end = off[n + 1];
        if (USE_E) {
            for (int p = beg; p < end; ++p) {
                int src = srcs[p];
                u16x8 xg = *(const u16x8*)&xin[((size_t)src << 8) + ((nl ^ (src & 7)) << 3)];
#if HAVE_FP8
                uint2 eg = ((const uint2*)eprec)[(size_t)p * 32 + nl];
                f32x2 e01 = __builtin_amdgcn_cvt_pk_f32_fp8((int)eg.x, false);
                f32x2 e23 = __builtin_amdgcn_cvt_pk_f32_fp8((int)eg.x, true);
                f32x2 e45 = __builtin_amdgcn_cvt_pk_f32_fp8((int)eg.y, false);
                f32x2 e67 = __builtin_amdgcn_cvt_pk_f32_fp8((int)eg.y, true);
                float ev[8] = {e01[0], e01[1], e23[0], e23[1],
                               e45[0], e45[1], e67[0], e67[1]};
#else
                u16x8 eg = *(const u16x8*)&((const ushort_t*)eprec)[((size_t)p << 8) + nl * 8];
                float ev[8];
                #pragma unroll
                for (int j = 0; j < 8; ++j) ev[j] = bf2f(eg[j]);
#endif
                #pragma unroll
                for (int j = 0; j < 8; ++j)
                    acc[j] += fmaxf(bf2f(xg[j]) + ev[j], 0.f);
            }
        } else {
            for (int p = beg; p < end; ++p) {
                int src = srcs[p];
                float4 av = eaf[p];
                u16x8 xg = *(const u16x8*)&xin[((size_t)src << 8) + ((nl ^ (src & 7)) << 3)];
                #pragma unroll
                for (int j = 0; j < 8; ++j) {
                    float e = silu_f(bev[j] + av.x * wv[0][j] + av.y * wv[1][j]
                                            + av.z * wv[2][j] + av.w * wv[3][j]);
                    acc[j] += fmaxf(bf2f(xg[j]) + e, 0.f);
                }
            }
        }
        u16x8 o8;
        #pragma unroll
        for (int j = 0; j < 8; ++j) o8[j] = f2bf(acc[j]);
        *(u16x8*)&U[((size_t)n << 8) + ((nl ^ (n & 7)) << 3)] = o8;
    }
}

// ---------------- MLP + LN: out = LN(xin + (silu(U@W1+b1))@W2 + b2)
// r12 structure; __launch_bounds__(512, 6): 6 waves/EU -> 3 blocks/CU (reg cap ~84,
// usage ~56 incl AGPR -> no spill), +50% TLP for latency hiding.
template<int LAST>
__global__ __launch_bounds__(512, 6) void mlp_kernel(
    const ushort_t* U, const ushort_t* __restrict__ Wc1,
    const ushort_t* __restrict__ Wc2, const float* __restrict__ b1,
    const float* __restrict__ b2, const float* __restrict__ lng,
    const float* __restrict__ lnb, const ushort_t* __restrict__ xin,
    ushort_t* xout, float* __restrict__ xf32)
{
    __shared__ ushort_t sA[64][256];     // 32KB: U -> t -> h/v (swizzled cells)
    __shared__ float sGB[2][HDIM];       // 2KB gamma/beta
    const int tid = threadIdx.x;
    const int m0 = blockIdx.x * 64;
    const int lane = tid & 63;
    const int w = tid >> 6;
    const int lg = lane >> 4, ll = lane & 15;
    const int cb = w * 32;

    if (tid < HDIM) sGB[0][tid] = lng[tid];
    else sGB[1][tid - HDIM] = lnb[tid - HDIM];

    f32x4 bv1v[2], bv2v[2];
    #pragma unroll
    for (int nf = 0; nf < 2; ++nf) {
        int nb = cb + nf * 16 + lg * 4;
        bv1v[nf] = *(const f32x4*)&b1[nb];
        bv2v[nf] = *(const f32x4*)&b2[nb];
    }

    // ---- stage U tile (linear; global pre-swizzled)
    #pragma unroll
    for (int it = 0; it < 4; ++it) {
        int idx = tid + it * 512;
        *(u32x4*)((ushort_t*)sA + (idx << 3)) =
            *(const u32x4*)(U + (((size_t)m0) << 8) + (idx << 3));
    }
    __syncthreads();

    f32x4 acc[4][2] = {};
    const ushort_t* wp1 = Wc1 + w * 1024 + lane * 8;
    const ushort_t* wp2 = Wc2 + w * 1024 + lane * 8;
    bf16x8 wbuf[2][2];
    wbuf[0][0] = *(const bf16x8*)(wp1);
    wbuf[0][1] = *(const bf16x8*)(wp1 + 512);

    // ---- GEMM1 (reg prefetch; last iter prefetches W2 chunk0); W as A-operand
    #pragma unroll
    for (int p = 0; p < 8; ++p) {
        const ushort_t* nsrc = (p < 7) ? (wp1 + (p + 1) * 8192) : wp2;
        wbuf[(p + 1) & 1][0] = *(const bf16x8*)(nsrc);
        wbuf[(p + 1) & 1][1] = *(const bf16x8*)(nsrc + 512);
        bf16x8 af[4];
        #pragma unroll
        for (int m = 0; m < 4; ++m) {
            int r = m * 16 + ll;
            af[m] = *(const bf16x8*)&sA[r][(((p * 4 + lg) ^ (r & 7)) << 3)];
        }
        #pragma unroll
        for (int m = 0; m < 4; ++m)
            #pragma unroll
            for (int nf = 0; nf < 2; ++nf)
                acc[m][nf] = __builtin_amdgcn_mfma_f32_16x16x32_bf16(
                    wbuf[p & 1][nf], af[m], acc[m][nf], 0, 0, 0);
    }
    __syncthreads();   // all waves done reading sA(U)

    // ---- t = silu(acc + b1) -> sA via ds_write_b64; reset acc
    #pragma unroll
    for (int m = 0; m < 4; ++m) {
        int r = m * 16 + ll, rx = r & 7;
        #pragma unroll
        for (int nf = 0; nf < 2; ++nf) {
            int chunk = ((cb + nf * 16) >> 3) + (lg >> 1);
            int celloff = ((chunk ^ rx) << 3) + (lg & 1) * 4;
            ushort4 o;
            o.x = f2bf(silu_f(acc[m][nf][0] + bv1v[nf][0]));
            o.y = f2bf(silu_f(acc[m][nf][1] + bv1v[nf][1]));
            o.z = f2bf(silu_f(acc[m][nf][2] + bv1v[nf][2]));
            o.w = f2bf(silu_f(acc[m][nf][3] + bv1v[nf][3]));
            *(ushort4*)&sA[r][celloff] = o;
            acc[m][nf][0] = 0.f; acc[m][nf][1] = 0.f;
            acc[m][nf][2] = 0.f; acc[m][nf][3] = 0.f;
        }
    }
    __syncthreads();   // t visible

    // ---- GEMM2
    #pragma unroll
    for (int p = 0; p < 8; ++p) {
        if (p < 7) {
            wbuf[(p + 1) & 1][0] = *(const bf16x8*)(wp2 + (p + 1) * 8192);
            wbuf[(p + 1) & 1][1] = *(const bf16x8*)(wp2 + (p + 1) * 8192 + 512);
        }
        bf16x8 af[4];
        #pragma unroll
        for (int m = 0; m < 4; ++m) {
            int r = m * 16 + ll;
            af[m] = *(const bf16x8*)&sA[r][(((p * 4 + lg) ^ (r & 7)) << 3)];
        }
        #pragma unroll
        for (int m = 0; m < 4; ++m)
            #pragma unroll
            for (int nf = 0; nf < 2; ++nf)
                acc[m][nf] = __builtin_amdgcn_mfma_f32_16x16x32_bf16(
                    wbuf[p & 1][nf], af[m], acc[m][nf], 0, 0, 0);
    }
    __syncthreads();   // all waves done reading sA(t)

    // ---- h = acc + b2 -> sA cells (ds_write_b64)
    #pragma unroll
    for (int m = 0; m < 4; ++m) {
        int r = m * 16 + ll, rx = r & 7;
        #pragma unroll
        for (int nf = 0; nf < 2; ++nf) {
            int chunk = ((cb + nf * 16) >> 3) + (lg >> 1);
            int celloff = ((chunk ^ rx) << 3) + (lg & 1) * 4;
            ushort4 o;
            o.x = f2bf(acc[m][nf][0] + bv2v[nf][0]);
            o.y = f2bf(acc[m][nf][1] + bv2v[nf][1]);
            o.z = f2bf(acc[m][nf][2] + bv2v[nf][2]);
            o.w = f2bf(acc[m][nf][3] + bv2v[nf][3]);
            *(ushort4*)&sA[r][celloff] = o;
        }
    }
    __syncthreads();   // h visible

    // ---- row-pass LN: 8 thr/row, rotation swizzle; x residual from global
    {
        int rr = tid >> 3, kk = tid & 7;
        int rot = (kk + rr) & 7;
        size_t rowb = ((size_t)(m0 + rr)) << 8;
        float s = 0.f, q = 0.f;
        #pragma unroll
        for (int i = 0; i < 4; ++i) {
            int slot = rot + 8 * i;
            u16x8 h8 = *(const u16x8*)&sA[rr][slot << 3];
            u16x8 x8 = *(const u16x8*)&xin[rowb + (slot << 3)];
            u16x8 v8;
            #pragma unroll
            for (int j = 0; j < 8; ++j) {
                float v = bf2f(h8[j]) + bf2f(x8[j]);
                s += v; q += v * v;
                v8[j] = f2bf(v);
            }
            *(u16x8*)&sA[rr][slot << 3] = v8;
        }
        #pragma unroll
        for (int o = 1; o < 8; o <<= 1) {
            s += __shfl_xor(s, o, 64);
            q += __shfl_xor(q, o, 64);
        }
        float mu = s * (1.0f / HDIM);
        float var = q * (1.0f / HDIM) - mu * mu;
        float rs = rsqrtf(var + 1e-5f);
        #pragma unroll
        for (int i = 0; i < 4; ++i) {
            int slot = rot + 8 * i;
            int chunk = slot ^ (rr & 7);
            u16x8 v8 = *(const u16x8*)&sA[rr][slot << 3];
            if (LAST) {
                float* xrow = xf32 + (((size_t)(m0 + rr)) << 8);
                f32x4 o0, o1;
                #pragma unroll
                for (int j = 0; j < 4; ++j) {
                    o0[j] = (bf2f(v8[j]) - mu) * rs * sGB[0][chunk * 8 + j]
                            + sGB[1][chunk * 8 + j];
                    o1[j] = (bf2f(v8[4 + j]) - mu) * rs * sGB[0][chunk * 8 + 4 + j]
                            + sGB[1][chunk * 8 + 4 + j];
                }
                *(f32x4*)&xrow[chunk * 8] = o0;
                *(f32x4*)&xrow[chunk * 8 + 4] = o1;
            } else {
                u16x8 o8;
                #pragma unroll
                for (int j = 0; j < 8; ++j)
                    o8[j] = f2bf((bf2f(v8[j]) - mu) * rs * sGB[0][chunk * 8 + j]
                                 + sGB[1][chunk * 8 + j]);
                *(u16x8*)&xout[rowb + (slot << 3)] = o8;
            }
        }
    }
}

extern "C" void kernel_launch(void* const* d_in, const int* in_sizes, int n_in,
                              void* d_out, int out_size, void* d_ws, size_t ws_size,
                              hipStream_t stream)
{
    const int*   z    = (const int*)d_in[0];
    const float* feat = (const float*)d_in[1];
    const int*   ei   = (const int*)d_in[2];
    const float* ea   = (const float*)d_in[3];
    const int*   batch= (const int*)d_in[4];
    const float* emb  = (const float*)d_in[5];
    const float* Wf   = (const float*)d_in[6];
    const float* bfv  = (const float*)d_in[7];
    const float* g0   = (const float*)d_in[8];
    const float* b0   = (const float*)d_in[9];
    const float* We   = (const float*)d_in[10];
    const float* be   = (const float*)d_in[11];
    const float* W1   = (const float*)d_in[12];
    const float* b1   = (const float*)d_in[13];
    const float* W2   = (const float*)d_in[14];
    const float* b2   = (const float*)d_in[15];
    const float* lng  = (const float*)d_in[16];
    const float* lnb  = (const float*)d_in[17];

    float* x    = (float*)d_out;
    float* outb = (float*)d_out + (size_t)NN * HDIM;

    char* ws = (char*)d_ws;
    ushort_t* xb0  = (ushort_t*)ws;                         // 102,400,000 B
    ushort_t* xb1  = (ushort_t*)(ws + 102400000);           // 102,400,000 B
    float4*   eaf  = (float4*)(ws + 204800000);             // 6,400,000 B
    int*      srcs = (int*)(ws + 211200000);                // 1,600,000 B
    int*      off  = (int*)(ws + 212800000);                // 800,016 B
    int*      cursor = (int*)(ws + 213600016);              // 800,000 B
    int*      deg  = (int*)(ws + 214400016);                // 800,000 B
    int*      psum = (int*)(ws + 215200016);                // 1,008 B
    ushort_t* Wc1  = (ushort_t*)(ws + 215201024);           // 524,288 B
    ushort_t* Wc2  = (ushort_t*)(ws + 215725312);           // 524,288 B
    ushort_t* Wfc  = (ushort_t*)(ws + 216249600);           // 16,384 B
    void*     eprec= (void*)(ws + 216265984);               // fp8: 102.4MB / bf16: 204.8MB
#if HAVE_FP8
    const size_t eneed = (size_t)216265984 + (size_t)EE * 256;
#else
    const size_t eneed = (size_t)216265984 + (size_t)EE * 512;
#endif
    const int use_e = (ws_size >= eneed) ? 1 : 0;

    prep_w_kernel<<<2048, 256, 0, stream>>>(W1, W2, Wc1, Wc2);
    prep_wf_kernel<<<32, 256, 0, stream>>>(Wf, Wfc);
    batch_out_kernel<<<782, 256, 0, stream>>>(batch, outb);
    node_init_kernel<<<NN / 64, 512, 0, stream>>>(z, feat, emb, Wfc, bfv, g0, b0, xb0);

    hipMemsetAsync(deg, 0, NN * sizeof(int), stream);
    hist_kernel<<<1563, 256, 0, stream>>>(ei, deg);
    scan_blocks_kernel<<<196, 256, 0, stream>>>(deg, off, psum);
    scan_top_kernel<<<1, 256, 0, stream>>>(psum, 196);
    scan_add_kernel<<<782, 256, 0, stream>>>(off, psum, cursor);
    scatter_kernel<<<1563, 256, 0, stream>>>(ei, ea, cursor, srcs, eaf);
    if (use_e)
        edge_mlp_kernel<<<EE / 8, 256, 0, stream>>>(eaf, We, be, eprec);

    // ping-pong: layer l reads x=buf[l&1]; agg writes U into buf[(l+1)&1];
    // mlp writes its output IN PLACE over U (blocks touch only their own rows).
    ushort_t* xbuf[2] = {xb0, xb1};
    for (int l = 0; l < LL; ++l) {
        ushort_t* xin = xbuf[l & 1];
        ushort_t* Ub  = xbuf[(l + 1) & 1];
        if (use_e)
            agg_kernel<1><<<2048, 256, 0, stream>>>(off, srcs, eprec, eaf, We, be, xin, Ub);
        else
            agg_kernel<0><<<2048, 256, 0, stream>>>(off, srcs, eprec, eaf, We, be, xin, Ub);
        if (l == LL - 1) {
            mlp_kernel<1><<<NN / 64, 512, 0, stream>>>(
                Ub, Wc1 + l * 65536, Wc2 + l * 65536, b1 + l * HDIM, b2 + l * HDIM,
                lng + l * HDIM, lnb + l * HDIM, xin, Ub, x);
        } else {
            mlp_kernel<0><<<NN / 64, 512, 0, stream>>>(
                Ub, Wc1 + l * 65536, Wc2 + l * 65536, b1 + l * HDIM, b2 + l * HDIM,
                lng + l * HDIM, lnb + l * HDIM, xin, Ub, nullptr);
        }
    }
}

// Round 16
// 902.441 us; speedup vs baseline: 1.2132x; 1.0654x over previous
//
#include <hip/hip_runtime.h>
#include <hip/hip_bf16.h>

#define NN 200000
#define EE 400000
#define HDIM 256
#define LL 4
#define FEAT 10

#if defined(__has_builtin)
#if __has_builtin(__builtin_amdgcn_cvt_pk_fp8_f32) && __has_builtin(__builtin_amdgcn_cvt_pk_f32_fp8)
#define HAVE_FP8 1
#endif
#endif
#ifndef HAVE_FP8
#define HAVE_FP8 0
#endif

typedef unsigned short ushort_t;
typedef __attribute__((ext_vector_type(8))) short bf16x8;
typedef __attribute__((ext_vector_type(8))) unsigned short u16x8;
typedef __attribute__((ext_vector_type(2))) float f32x2;
typedef __attribute__((ext_vector_type(4))) float f32x4;
typedef __attribute__((ext_vector_type(4))) unsigned int u32x4;

__device__ inline ushort_t f2bf(float f) {
    unsigned int u = __builtin_bit_cast(unsigned int, f);
    return (ushort_t)((u + 0x7fffu + ((u >> 16) & 1u)) >> 16);
}
__device__ inline float bf2f(ushort_t s) {
    unsigned int u = ((unsigned int)s) << 16;
    return __builtin_bit_cast(float, u);
}
__device__ inline float silu_f(float v) { return v / (1.0f + __expf(-v)); }

// x global layout PRE-SWIZZLED: row n, 16B-chunk slot s holds true chunk s ^ (n&7).
// U (fp8) layout: row n, 8B-slot s holds true 8-col chunk s ^ (n&7).

// ---------------- Wf pre-pack: A-operand fragment layout, single K=32 chunk (k>=10 -> 0)
__global__ __launch_bounds__(256) void prep_wf_kernel(
    const float* __restrict__ Wf, ushort_t* __restrict__ Wfc)
{
    int idx = blockIdx.x * 256 + threadIdx.x;   // 8192
    if (idx >= 8192) return;
    int e = idx & 7;
    int lane = (idx >> 3) & 63;
    int nf = (idx >> 9) & 1;
    int w8 = idx >> 10;
    int n = w8 * 32 + nf * 16 + (lane & 15);
    int k = (lane >> 4) * 8 + e;
    Wfc[idx] = (k < FEAT) ? f2bf(Wf[k * HDIM + n]) : (ushort_t)0;
}

// ---------------- node init via MFMA: xb = LN(silu(emb[z] + feat@Wf + bf))
__global__ __launch_bounds__(512, 4) void node_init_kernel(
    const int* __restrict__ z, const float* __restrict__ feat,
    const float* __restrict__ emb, const ushort_t* __restrict__ Wfc,
    const float* __restrict__ bfv, const float* __restrict__ g0,
    const float* __restrict__ b0, ushort_t* __restrict__ xb)
{
    __shared__ ushort_t sA[64][256];
    __shared__ float sGB[2][HDIM];
    const int tid = threadIdx.x;
    const int m0 = blockIdx.x * 64;
    const int lane = tid & 63;
    const int w = tid >> 6;
    const int lg = lane >> 4, ll = lane & 15;
    const int cb = w * 32;

    if (tid < HDIM) sGB[0][tid] = g0[tid];
    else sGB[1][tid - HDIM] = b0[tid - HDIM];

    f32x4 bvv[2];
    #pragma unroll
    for (int nf = 0; nf < 2; ++nf)
        bvv[nf] = *(const f32x4*)&bfv[cb + nf * 16 + lg * 4];

    bf16x8 wf[2];
    wf[0] = *(const bf16x8*)(Wfc + w * 1024 + lane * 8);
    wf[1] = *(const bf16x8*)(Wfc + w * 1024 + 512 + lane * 8);

    bf16x8 af[4];
    #pragma unroll
    for (int m = 0; m < 4; ++m) {
        int gr = m0 + m * 16 + ll;
        bf16x8 t = {};
        if (lg == 0) {
            #pragma unroll
            for (int j = 0; j < 8; ++j) t[j] = (short)f2bf(feat[gr * FEAT + j]);
        } else if (lg == 1) {
            t[0] = (short)f2bf(feat[gr * FEAT + 8]);
            t[1] = (short)f2bf(feat[gr * FEAT + 9]);
        }
        af[m] = t;
    }

    f32x4 acc[4][2] = {};
    #pragma unroll
    for (int m = 0; m < 4; ++m)
        #pragma unroll
        for (int nf = 0; nf < 2; ++nf)
            acc[m][nf] = __builtin_amdgcn_mfma_f32_16x16x32_bf16(
                wf[nf], af[m], acc[m][nf], 0, 0, 0);

    #pragma unroll
    for (int m = 0; m < 4; ++m) {
        int r = m * 16 + ll, rx = r & 7;
        int zi = z[m0 + r];
        #pragma unroll
        for (int nf = 0; nf < 2; ++nf) {
            int n0 = cb + nf * 16 + lg * 4;
            f32x4 ev = *(const f32x4*)&emb[(size_t)zi * HDIM + n0];
            int chunk = ((cb + nf * 16) >> 3) + (lg >> 1);
            int celloff = ((chunk ^ rx) << 3) + (lg & 1) * 4;
            ushort4 o;
            o.x = f2bf(silu_f(acc[m][nf][0] + ev[0] + bvv[nf][0]));
            o.y = f2bf(silu_f(acc[m][nf][1] + ev[1] + bvv[nf][1]));
            o.z = f2bf(silu_f(acc[m][nf][2] + ev[2] + bvv[nf][2]));
            o.w = f2bf(silu_f(acc[m][nf][3] + ev[3] + bvv[nf][3]));
            *(ushort4*)&sA[r][celloff] = o;
        }
    }
    __syncthreads();

    {
        int rr = tid >> 3, kk = tid & 7;
        int rot = (kk + rr) & 7;
        size_t rowb = ((size_t)(m0 + rr)) << 8;
        u16x8 v8[4];
        float s = 0.f, q = 0.f;
        #pragma unroll
        for (int i = 0; i < 4; ++i) {
            int slot = rot + 8 * i;
            v8[i] = *(const u16x8*)&sA[rr][slot << 3];
            #pragma unroll
            for (int j = 0; j < 8; ++j) {
                float v = bf2f(v8[i][j]);
                s += v; q += v * v;
            }
        }
        #pragma unroll
        for (int o = 1; o < 8; o <<= 1) {
            s += __shfl_xor(s, o, 64);
            q += __shfl_xor(q, o, 64);
        }
        float mu = s * (1.0f / HDIM);
        float var = q * (1.0f / HDIM) - mu * mu;
        float rs = rsqrtf(var + 1e-5f);
        #pragma unroll
        for (int i = 0; i < 4; ++i) {
            int slot = rot + 8 * i;
            int chunk = slot ^ (rr & 7);
            u16x8 o8;
            #pragma unroll
            for (int j = 0; j < 8; ++j)
                o8[j] = f2bf((bf2f(v8[i][j]) - mu) * rs * sGB[0][chunk * 8 + j]
                             + sGB[1][chunk * 8 + j]);
            *(u16x8*)&xb[rowb + (slot << 3)] = o8;
        }
    }
}

__global__ __launch_bounds__(256) void batch_out_kernel(
    const int* __restrict__ batch, float* __restrict__ out)
{
    int i = blockIdx.x * 256 + threadIdx.x;
    if (i < NN) out[i] = (float)batch[i];
}

// ---------------- CSR build
__global__ __launch_bounds__(256) void hist_kernel(const int* __restrict__ ei, int* __restrict__ deg)
{
    int i = blockIdx.x * 256 + threadIdx.x;
    if (i < EE) atomicAdd(&deg[ei[EE + i]], 1);
}

__global__ __launch_bounds__(256) void scan_blocks_kernel(
    const int* __restrict__ deg, int* __restrict__ off, int* __restrict__ psum)
{
    int blk = blockIdx.x, t = threadIdx.x;
    int base = blk * 1024 + t * 4;
    int v[4];
    #pragma unroll
    for (int i = 0; i < 4; ++i) v[i] = (base + i < NN) ? deg[base + i] : 0;
    int s = v[0] + v[1] + v[2] + v[3];
    int lane = t & 63, w = t >> 6;
    int ps = s;
    #pragma unroll
    for (int o = 1; o < 64; o <<= 1) { int u = __shfl_up(ps, o, 64); if (lane >= o) ps += u; }
    __shared__ int wt[4];
    if (lane == 63) wt[w] = ps;
    __syncthreads();
    int wbase = 0;
    for (int k = 0; k < w; ++k) wbase += wt[k];
    int run = wbase + ps - s;
    #pragma unroll
    for (int i = 0; i < 4; ++i) {
        if (base + i < NN) off[base + i] = run;
        run += v[i];
    }
    if (t == 255) psum[blk] = wbase + ps;
}

__global__ __launch_bounds__(256) void scan_top_kernel(int* __restrict__ psum, int nb)
{
    int t = threadIdx.x;
    int v = (t < nb) ? psum[t] : 0;
    int lane = t & 63, w = t >> 6;
    int ps = v;
    #pragma unroll
    for (int o = 1; o < 64; o <<= 1) { int u = __shfl_up(ps, o, 64); if (lane >= o) ps += u; }
    __shared__ int wt[4];
    if (lane == 63) wt[w] = ps;
    __syncthreads();
    int wbase = 0;
    for (int k = 0; k < w; ++k) wbase += wt[k];
    if (t < nb) psum[t] = wbase + ps - v;
}

__global__ __launch_bounds__(256) void scan_add_kernel(
    int* __restrict__ off, const int* __restrict__ psum, int* __restrict__ cursor)
{
    int i = blockIdx.x * 256 + threadIdx.x;
    if (i < NN) {
        int o = off[i] + psum[i >> 10];
        off[i] = o;
        cursor[i] = o;
        if (i == NN - 1) off[NN] = EE;
    }
}

__global__ __launch_bounds__(256) void scatter_kernel(
    const int* __restrict__ ei, const float* __restrict__ ea,
    int* __restrict__ cursor, int* __restrict__ srcs, float4* __restrict__ eaf)
{
    int i = blockIdx.x * 256 + threadIdx.x;
    if (i < EE) {
        int dst = ei[EE + i];
        int pos = atomicAdd(&cursor[dst], 1);
        srcs[pos] = ei[i];
        eaf[pos] = ((const float4*)ea)[i];
    }
}

// ---------------- edge MLP (layer-invariant): e = silu(eaf@We + be), CSR order.
__global__ __launch_bounds__(256) void edge_mlp_kernel(
    const float4* __restrict__ eaf, const float* __restrict__ We,
    const float* __restrict__ be, void* __restrict__ eout)
{
    int p = (blockIdx.x * 256 + threadIdx.x) >> 5;
    if (p >= EE) return;
    int nl = threadIdx.x & 31, c0 = nl * 8;
    float4 av = eaf[p];
    float v[8];
    #pragma unroll
    for (int j = 0; j < 8; ++j) {
        float t = be[c0 + j] + av.x * We[c0 + j] + av.y * We[HDIM + c0 + j]
                + av.z * We[2 * HDIM + c0 + j] + av.w * We[3 * HDIM + c0 + j];
        v[j] = silu_f(t);
    }
#if HAVE_FP8
    int t0 = __builtin_amdgcn_cvt_pk_fp8_f32(v[0], v[1], 0, false);
    t0 = __builtin_amdgcn_cvt_pk_fp8_f32(v[2], v[3], t0, true);
    int t1 = __builtin_amdgcn_cvt_pk_fp8_f32(v[4], v[5], 0, false);
    t1 = __builtin_amdgcn_cvt_pk_fp8_f32(v[6], v[7], t1, true);
    uint2 o;
    o.x = (unsigned int)t0;
    o.y = (unsigned int)t1;
    ((uint2*)eout)[(size_t)p * 32 + nl] = o;
#else
    u16x8 o8;
    #pragma unroll
    for (int j = 0; j < 8; ++j) o8[j] = f2bf(v[j]);
    *(u16x8*)&((ushort_t*)eout)[((size_t)p << 8) + nl * 8] = o8;
#endif
}

// ---------------- weights: W[l][k][n] f32 -> chunk-major per-wave (8 col-waves) bf16
__global__ __launch_bounds__(256) void prep_w_kernel(
    const float* __restrict__ W1, const float* __restrict__ W2,
    ushort_t* __restrict__ Wc1, ushort_t* __restrict__ Wc2)
{
    int idx = blockIdx.x * 256 + threadIdx.x;   // 2 * 4 * 65536
    int which = idx >> 18;
    int rem = idx & 0x3FFFF;
    int l = rem >> 16;
    int t = rem & 0xFFFF;
    int e = t & 7;
    int lane = (t >> 3) & 63;
    int nf = (t >> 9) & 1;
    int w8 = (t >> 10) & 7;
    int c = (t >> 13) & 7;
    int n = w8 * 32 + nf * 16 + (lane & 15);
    int k = c * 32 + (lane >> 4) * 8 + e;
    const float* W = which ? W2 : W1;
    ushort_t* Wc = which ? Wc2 : Wc1;
    Wc[rem] = f2bf(W[l * 65536 + k * 256 + n]);
}

// ---------------- aggregation: U = fp8(x_self + sum relu(x[src]+e)); 32-lane groups
template<int USE_E>
__global__ __launch_bounds__(256) void agg_kernel(
    const int* __restrict__ off, const int* __restrict__ srcs,
    const void* __restrict__ eprec, const float4* __restrict__ eaf,
    const float* __restrict__ We, const float* __restrict__ be,
    const ushort_t* __restrict__ xin, void* __restrict__ U)
{
    const int gstride = (gridDim.x * 256) >> 5;
    const int gid0 = (blockIdx.x * 256 + threadIdx.x) >> 5;
    const int nl = threadIdx.x & 31, c0 = nl * 8;
    float wv[4][8], bev[8];
    if (!USE_E) {
        #pragma unroll
        for (int r4 = 0; r4 < 4; ++r4)
            #pragma unroll
            for (int j = 0; j < 8; ++j) wv[r4][j] = We[r4 * HDIM + c0 + j];
        #pragma unroll
        for (int j = 0; j < 8; ++j) bev[j] = be[c0 + j];
    }

    for (int n = gid0; n < NN; n += gstride) {
        u16x8 xs = *(const u16x8*)&xin[((size_t)n << 8) + ((nl ^ (n & 7)) << 3)];
        float acc[8];
        #pragma unroll
        for (int j = 0; j < 8; ++j) acc[j] = bf2f(xs[j]);
        int beg = off[n], end = off[n + 1];
        if (USE_E) {
            for (int p = beg; p < end; ++p) {
                int src = srcs[p];
                u16x8 xg = *(const u16x8*)&xin[((size_t)src << 8) + ((nl ^ (src & 7)) << 3)];
#if HAVE_FP8
                uint2 eg = ((const uint2*)eprec)[(size_t)p * 32 + nl];
                f32x2 e01 = __builtin_amdgcn_cvt_pk_f32_fp8((int)eg.x, false);
                f32x2 e23 = __builtin_amdgcn_cvt_pk_f32_fp8((int)eg.x, true);
                f32x2 e45 = __builtin_amdgcn_cvt_pk_f32_fp8((int)eg.y, false);
                f32x2 e67 = __builtin_amdgcn_cvt_pk_f32_fp8((int)eg.y, true);
                float ev[8] = {e01[0], e01[1], e23[0], e23[1],
                               e45[0], e45[1], e67[0], e67[1]};
#else
                u16x8 eg = *(const u16x8*)&((const ushort_t*)eprec)[((size_t)p << 8) + nl * 8];
                float ev[8];
                #pragma unroll
                for (int j = 0; j < 8; ++j) ev[j] = bf2f(eg[j]);
#endif
                #pragma unroll
                for (int j = 0; j < 8; ++j)
                    acc[j] += fmaxf(bf2f(xg[j]) + ev[j], 0.f);
            }
        } else {
            for (int p = beg; p < end; ++p) {
                int src = srcs[p];
                float4 av = eaf[p];
                u16x8 xg = *(const u16x8*)&xin[((size_t)src << 8) + ((nl ^ (src & 7)) << 3)];
                #pragma unroll
                for (int j = 0; j < 8; ++j) {
                    float e = silu_f(bev[j] + av.x * wv[0][j] + av.y * wv[1][j]
                                            + av.z * wv[2][j] + av.w * wv[3][j]);
                    acc[j] += fmaxf(bf2f(xg[j]) + e, 0.f);
                }
            }
        }
#if HAVE_FP8
        int t0 = __builtin_amdgcn_cvt_pk_fp8_f32(acc[0], acc[1], 0, false);
        t0 = __builtin_amdgcn_cvt_pk_fp8_f32(acc[2], acc[3], t0, true);
        int t1 = __builtin_amdgcn_cvt_pk_fp8_f32(acc[4], acc[5], 0, false);
        t1 = __builtin_amdgcn_cvt_pk_fp8_f32(acc[6], acc[7], t1, true);
        uint2 o;
        o.x = (unsigned int)t0;
        o.y = (unsigned int)t1;
        ((uint2*)U)[((size_t)n << 5) + (nl ^ (n & 7))] = o;
#else
        u16x8 o8;
        #pragma unroll
        for (int j = 0; j < 8; ++j) o8[j] = f2bf(acc[j]);
        *(u16x8*)&((ushort_t*)U)[((size_t)n << 8) + ((nl ^ (n & 7)) << 3)] = o8;
#endif
    }
}

// ---------------- MLP + LN: out = LN(xin + (silu(U@W1+b1))@W2 + b2)
// U read as fp8 (converted to bf16 during LDS staging). U is a DEDICATED buffer,
// xout never aliases it. r12 GEMM structure, (512,4).
template<int LAST>
__global__ __launch_bounds__(512, 4) void mlp_kernel(
    const void* __restrict__ U, const ushort_t* __restrict__ Wc1,
    const ushort_t* __restrict__ Wc2, const float* __restrict__ b1,
    const float* __restrict__ b2, const float* __restrict__ lng,
    const float* __restrict__ lnb, const ushort_t* __restrict__ xin,
    ushort_t* __restrict__ xout, float* __restrict__ xf32)
{
    __shared__ ushort_t sA[64][256];     // 32KB: U -> t -> h/v (swizzled cells)
    __shared__ float sGB[2][HDIM];       // 2KB gamma/beta
    const int tid = threadIdx.x;
    const int m0 = blockIdx.x * 64;
    const int lane = tid & 63;
    const int w = tid >> 6;
    const int lg = lane >> 4, ll = lane & 15;
    const int cb = w * 32;

    if (tid < HDIM) sGB[0][tid] = lng[tid];
    else sGB[1][tid - HDIM] = lnb[tid - HDIM];

    f32x4 bv1v[2], bv2v[2];
    #pragma unroll
    for (int nf = 0; nf < 2; ++nf) {
        int nb = cb + nf * 16 + lg * 4;
        bv1v[nf] = *(const f32x4*)&b1[nb];
        bv2v[nf] = *(const f32x4*)&b2[nb];
    }

    // ---- stage U tile: fp8 global (pre-swizzled slots) -> bf16 sA cells
#if HAVE_FP8
    {
        const uint2* Uq = (const uint2*)U + (((size_t)m0) << 5);
        #pragma unroll
        for (int it = 0; it < 4; ++it) {
            int idx = tid + it * 512;            // 0..2047 = row*32 + slot
            uint2 v = Uq[idx];
            f32x2 a0 = __builtin_amdgcn_cvt_pk_f32_fp8((int)v.x, false);
            f32x2 a1 = __builtin_amdgcn_cvt_pk_f32_fp8((int)v.x, true);
            f32x2 a2 = __builtin_amdgcn_cvt_pk_f32_fp8((int)v.y, false);
            f32x2 a3 = __builtin_amdgcn_cvt_pk_f32_fp8((int)v.y, true);
            u16x8 o;
            o[0] = f2bf(a0[0]); o[1] = f2bf(a0[1]);
            o[2] = f2bf(a1[0]); o[3] = f2bf(a1[1]);
            o[4] = f2bf(a2[0]); o[5] = f2bf(a2[1]);
            o[6] = f2bf(a3[0]); o[7] = f2bf(a3[1]);
            *(u16x8*)((ushort_t*)sA + (idx << 3)) = o;
        }
    }
#else
    #pragma unroll
    for (int it = 0; it < 4; ++it) {
        int idx = tid + it * 512;
        *(u32x4*)((ushort_t*)sA + (idx << 3)) =
            *(const u32x4*)((const ushort_t*)U + (((size_t)m0) << 8) + (idx << 3));
    }
#endif
    __syncthreads();

    f32x4 acc[4][2] = {};
    const ushort_t* wp1 = Wc1 + w * 1024 + lane * 8;
    const ushort_t* wp2 = Wc2 + w * 1024 + lane * 8;
    bf16x8 wbuf[2][2];
    wbuf[0][0] = *(const bf16x8*)(wp1);
    wbuf[0][1] = *(const bf16x8*)(wp1 + 512);

    // ---- GEMM1 (reg prefetch; last iter prefetches W2 chunk0); W as A-operand
    #pragma unroll
    for (int p = 0; p < 8; ++p) {
        const ushort_t* nsrc = (p < 7) ? (wp1 + (p + 1) * 8192) : wp2;
        wbuf[(p + 1) & 1][0] = *(const bf16x8*)(nsrc);
        wbuf[(p + 1) & 1][1] = *(const bf16x8*)(nsrc + 512);
        bf16x8 af[4];
        #pragma unroll
        for (int m = 0; m < 4; ++m) {
            int r = m * 16 + ll;
            af[m] = *(const bf16x8*)&sA[r][(((p * 4 + lg) ^ (r & 7)) << 3)];
        }
        #pragma unroll
        for (int m = 0; m < 4; ++m)
            #pragma unroll
            for (int nf = 0; nf < 2; ++nf)
                acc[m][nf] = __builtin_amdgcn_mfma_f32_16x16x32_bf16(
                    wbuf[p & 1][nf], af[m], acc[m][nf], 0, 0, 0);
    }
    __syncthreads();   // all waves done reading sA(U)

    // ---- t = silu(acc + b1) -> sA via ds_write_b64; reset acc
    #pragma unroll
    for (int m = 0; m < 4; ++m) {
        int r = m * 16 + ll, rx = r & 7;
        #pragma unroll
        for (int nf = 0; nf < 2; ++nf) {
            int chunk = ((cb + nf * 16) >> 3) + (lg >> 1);
            int celloff = ((chunk ^ rx) << 3) + (lg & 1) * 4;
            ushort4 o;
            o.x = f2bf(silu_f(acc[m][nf][0] + bv1v[nf][0]));
            o.y = f2bf(silu_f(acc[m][nf][1] + bv1v[nf][1]));
            o.z = f2bf(silu_f(acc[m][nf][2] + bv1v[nf][2]));
            o.w = f2bf(silu_f(acc[m][nf][3] + bv1v[nf][3]));
            *(ushort4*)&sA[r][celloff] = o;
            acc[m][nf][0] = 0.f; acc[m][nf][1] = 0.f;
            acc[m][nf][2] = 0.f; acc[m][nf][3] = 0.f;
        }
    }
    __syncthreads();   // t visible

    // ---- GEMM2
    #pragma unroll
    for (int p = 0; p < 8; ++p) {
        if (p < 7) {
            wbuf[(p + 1) & 1][0] = *(const bf16x8*)(wp2 + (p + 1) * 8192);
            wbuf[(p + 1) & 1][1] = *(const bf16x8*)(wp2 + (p + 1) * 8192 + 512);
        }
        bf16x8 af[4];
        #pragma unroll
        for (int m = 0; m < 4; ++m) {
            int r = m * 16 + ll;
            af[m] = *(const bf16x8*)&sA[r][(((p * 4 + lg) ^ (r & 7)) << 3)];
        }
        #pragma unroll
        for (int m = 0; m < 4; ++m)
            #pragma unroll
            for (int nf = 0; nf < 2; ++nf)
                acc[m][nf] = __builtin_amdgcn_mfma_f32_16x16x32_bf16(
                    wbuf[p & 1][nf], af[m], acc[m][nf], 0, 0, 0);
    }
    __syncthreads();   // all waves done reading sA(t)

    // ---- h = acc + b2 -> sA cells (ds_write_b64)
    #pragma unroll
    for (int m = 0; m < 4; ++m) {
        int r = m * 16 + ll, rx = r & 7;
        #pragma unroll
        for (int nf = 0; nf < 2; ++nf) {
            int chunk = ((cb + nf * 16) >> 3) + (lg >> 1);
            int celloff = ((chunk ^ rx) << 3) + (lg & 1) * 4;
            ushort4 o;
            o.x = f2bf(acc[m][nf][0] + bv2v[nf][0]);
            o.y = f2bf(acc[m][nf][1] + bv2v[nf][1]);
            o.z = f2bf(acc[m][nf][2] + bv2v[nf][2]);
            o.w = f2bf(acc[m][nf][3] + bv2v[nf][3]);
            *(ushort4*)&sA[r][celloff] = o;
        }
    }
    __syncthreads();   // h visible

    // ---- row-pass LN: 8 thr/row, rotation swizzle; x residual from global
    {
        int rr = tid >> 3, kk = tid & 7;
        int rot = (kk + rr) & 7;
        size_t rowb = ((size_t)(m0 + rr)) << 8;
        float s = 0.f, q = 0.f;
        #pragma unroll
        for (int i = 0; i < 4; ++i) {
            int slot = rot + 8 * i;
            u16x8 h8 = *(const u16x8*)&sA[rr][slot << 3];
            u16x8 x8 = *(const u16x8*)&xin[rowb + (slot << 3)];
            u16x8 v8;
            #pragma unroll
            for (int j = 0; j < 8; ++j) {
                float v = bf2f(h8[j]) + bf2f(x8[j]);
                s += v; q += v * v;
                v8[j] = f2bf(v);
            }
            *(u16x8*)&sA[rr][slot << 3] = v8;
        }
        #pragma unroll
        for (int o = 1; o < 8; o <<= 1) {
            s += __shfl_xor(s, o, 64);
            q += __shfl_xor(q, o, 64);
        }
        float mu = s * (1.0f / HDIM);
        float var = q * (1.0f / HDIM) - mu * mu;
        float rs = rsqrtf(var + 1e-5f);
        #pragma unroll
        for (int i = 0; i < 4; ++i) {
            int slot = rot + 8 * i;
            int chunk = slot ^ (rr & 7);
            u16x8 v8 = *(const u16x8*)&sA[rr][slot << 3];
            if (LAST) {
                float* xrow = xf32 + (((size_t)(m0 + rr)) << 8);
                f32x4 o0, o1;
                #pragma unroll
                for (int j = 0; j < 4; ++j) {
                    o0[j] = (bf2f(v8[j]) - mu) * rs * sGB[0][chunk * 8 + j]
                            + sGB[1][chunk * 8 + j];
                    o1[j] = (bf2f(v8[4 + j]) - mu) * rs * sGB[0][chunk * 8 + 4 + j]
                            + sGB[1][chunk * 8 + 4 + j];
                }
                *(f32x4*)&xrow[chunk * 8] = o0;
                *(f32x4*)&xrow[chunk * 8 + 4] = o1;
            } else {
                u16x8 o8;
                #pragma unroll
                for (int j = 0; j < 8; ++j)
                    o8[j] = f2bf((bf2f(v8[j]) - mu) * rs * sGB[0][chunk * 8 + j]
                                 + sGB[1][chunk * 8 + j]);
                *(u16x8*)&xout[rowb + (slot << 3)] = o8;
            }
        }
    }
}

extern "C" void kernel_launch(void* const* d_in, const int* in_sizes, int n_in,
                              void* d_out, int out_size, void* d_ws, size_t ws_size,
                              hipStream_t stream)
{
    const int*   z    = (const int*)d_in[0];
    const float* feat = (const float*)d_in[1];
    const int*   ei   = (const int*)d_in[2];
    const float* ea   = (const float*)d_in[3];
    const int*   batch= (const int*)d_in[4];
    const float* emb  = (const float*)d_in[5];
    const float* Wf   = (const float*)d_in[6];
    const float* bfv  = (const float*)d_in[7];
    const float* g0   = (const float*)d_in[8];
    const float* b0   = (const float*)d_in[9];
    const float* We   = (const float*)d_in[10];
    const float* be   = (const float*)d_in[11];
    const float* W1   = (const float*)d_in[12];
    const float* b1   = (const float*)d_in[13];
    const float* W2   = (const float*)d_in[14];
    const float* b2   = (const float*)d_in[15];
    const float* lng  = (const float*)d_in[16];
    const float* lnb  = (const float*)d_in[17];

    float* x    = (float*)d_out;
    float* outb = (float*)d_out + (size_t)NN * HDIM;

    char* ws = (char*)d_ws;
    ushort_t* xb0  = (ushort_t*)ws;                         // 102,400,000 B
    ushort_t* xb1  = (ushort_t*)(ws + 102400000);           // 102,400,000 B
    float4*   eaf  = (float4*)(ws + 204800000);             // 6,400,000 B
    int*      srcs = (int*)(ws + 211200000);                // 1,600,000 B
    int*      off  = (int*)(ws + 212800000);                // 800,016 B
    int*      cursor = (int*)(ws + 213600016);              // 800,000 B
    int*      deg  = (int*)(ws + 214400016);                // 800,000 B
    int*      psum = (int*)(ws + 215200016);                // 1,008 B
    ushort_t* Wc1  = (ushort_t*)(ws + 215201024);           // 524,288 B
    ushort_t* Wc2  = (ushort_t*)(ws + 215725312);           // 524,288 B
    ushort_t* Wfc  = (ushort_t*)(ws + 216249600);           // 16,384 B
    void*     Ubuf = (void*)(ws + 216265984);               // fp8: 51.2MB / bf16: 102.4MB
#if HAVE_FP8
    char*     ep   = ws + 216265984 + 51200000;
    const size_t eneed = (size_t)(216265984 + 51200000) + (size_t)EE * 256;
#else
    char*     ep   = ws + 216265984 + 102400000;
    const size_t eneed = (size_t)(216265984 + 102400000) + (size_t)EE * 512;
#endif
    void* eprec = (void*)ep;
    const int use_e = (ws_size >= eneed) ? 1 : 0;

    prep_w_kernel<<<2048, 256, 0, stream>>>(W1, W2, Wc1, Wc2);
    prep_wf_kernel<<<32, 256, 0, stream>>>(Wf, Wfc);
    batch_out_kernel<<<782, 256, 0, stream>>>(batch, outb);
    node_init_kernel<<<NN / 64, 512, 0, stream>>>(z, feat, emb, Wfc, bfv, g0, b0, xb0);

    hipMemsetAsync(deg, 0, NN * sizeof(int), stream);
    hist_kernel<<<1563, 256, 0, stream>>>(ei, deg);
    scan_blocks_kernel<<<196, 256, 0, stream>>>(deg, off, psum);
    scan_top_kernel<<<1, 256, 0, stream>>>(psum, 196);
    scan_add_kernel<<<782, 256, 0, stream>>>(off, psum, cursor);
    scatter_kernel<<<1563, 256, 0, stream>>>(ei, ea, cursor, srcs, eaf);
    if (use_e)
        edge_mlp_kernel<<<EE / 8, 256, 0, stream>>>(eaf, We, be, eprec);

    // x ping-pong between xb0/xb1; U (fp8) lives in its OWN buffer (no aliasing).
    ushort_t* xbuf[2] = {xb0, xb1};
    for (int l = 0; l < LL; ++l) {
        ushort_t* xin  = xbuf[l & 1];
        ushort_t* xout = xbuf[(l + 1) & 1];
        if (use_e)
            agg_kernel<1><<<2048, 256, 0, stream>>>(off, srcs, eprec, eaf, We, be, xin, Ubuf);
        else
            agg_kernel<0><<<2048, 256, 0, stream>>>(off, srcs, eprec, eaf, We, be, xin, Ubuf);
        if (l == LL - 1) {
            mlp_kernel<1><<<NN / 64, 512, 0, stream>>>(
                Ubuf, Wc1 + l * 65536, Wc2 + l * 65536, b1 + l * HDIM, b2 + l * HDIM,
                lng + l * HDIM, lnb + l * HDIM, xin, xout, x);
        } else {
            mlp_kernel<0><<<NN / 64, 512, 0, stream>>>(
                Ubuf, Wc1 + l * 65536, Wc2 + l * 65536, b1 + l * HDIM, b2 + l * HDIM,
                lng + l * HDIM, lnb + l * HDIM, xin, xout, nullptr);
        }
    }
}

// Round 17
// 788.133 us; speedup vs baseline: 1.3892x; 1.1450x over previous
//
#include <hip/hip_runtime.h>
#include <hip/hip_bf16.h>

#define NN 200000
#define EE 400000
#define HDIM 256
#define LL 4
#define FEAT 10

#if defined(__has_builtin)
#if __has_builtin(__builtin_amdgcn_cvt_pk_fp8_f32) && __has_builtin(__builtin_amdgcn_cvt_pk_f32_fp8)
#define HAVE_FP8 1
#endif
#endif
#ifndef HAVE_FP8
#define HAVE_FP8 0
#endif

typedef unsigned short ushort_t;
typedef __attribute__((ext_vector_type(8))) short bf16x8;
typedef __attribute__((ext_vector_type(8))) unsigned short u16x8;
typedef __attribute__((ext_vector_type(2))) float f32x2;
typedef __attribute__((ext_vector_type(4))) float f32x4;
typedef __attribute__((ext_vector_type(4))) unsigned int u32x4;

__device__ inline ushort_t f2bf(float f) {
    unsigned int u = __builtin_bit_cast(unsigned int, f);
    return (ushort_t)((u + 0x7fffu + ((u >> 16) & 1u)) >> 16);
}
__device__ inline float bf2f(ushort_t s) {
    unsigned int u = ((unsigned int)s) << 16;
    return __builtin_bit_cast(float, u);
}
__device__ inline float silu_f(float v) { return v / (1.0f + __expf(-v)); }

// ---- x / U storage: fp8 when available (8 cols -> uint2), else bf16 (8 cols -> u16x8).
// Row layout: slot s (8-col granule) holds true 8-col chunk s ^ (n&7), s in [0,32).
#if HAVE_FP8
#define XROW_SHIFT 5
__device__ inline void x8_load(const void* base, size_t idx, float* f) {
    uint2 v = ((const uint2*)base)[idx];
    f32x2 a0 = __builtin_amdgcn_cvt_pk_f32_fp8((int)v.x, false);
    f32x2 a1 = __builtin_amdgcn_cvt_pk_f32_fp8((int)v.x, true);
    f32x2 a2 = __builtin_amdgcn_cvt_pk_f32_fp8((int)v.y, false);
    f32x2 a3 = __builtin_amdgcn_cvt_pk_f32_fp8((int)v.y, true);
    f[0]=a0[0]; f[1]=a0[1]; f[2]=a1[0]; f[3]=a1[1];
    f[4]=a2[0]; f[5]=a2[1]; f[6]=a3[0]; f[7]=a3[1];
}
__device__ inline void x8_store(void* base, size_t idx, const float* f) {
    int t0 = __builtin_amdgcn_cvt_pk_fp8_f32(f[0], f[1], 0, false);
    t0 = __builtin_amdgcn_cvt_pk_fp8_f32(f[2], f[3], t0, true);
    int t1 = __builtin_amdgcn_cvt_pk_fp8_f32(f[4], f[5], 0, false);
    t1 = __builtin_amdgcn_cvt_pk_fp8_f32(f[6], f[7], t1, true);
    uint2 o; o.x = (unsigned int)t0; o.y = (unsigned int)t1;
    ((uint2*)base)[idx] = o;
}
#else
#define XROW_SHIFT 5
__device__ inline void x8_load(const void* base, size_t idx, float* f) {
    u16x8 v = ((const u16x8*)base)[idx];
    #pragma unroll
    for (int j = 0; j < 8; ++j) f[j] = bf2f(v[j]);
}
__device__ inline void x8_store(void* base, size_t idx, const float* f) {
    u16x8 o;
    #pragma unroll
    for (int j = 0; j < 8; ++j) o[j] = f2bf(f[j]);
    ((u16x8*)base)[idx] = o;
}
#endif

// ---------------- Wf pre-pack: A-operand fragment layout, single K=32 chunk (k>=10 -> 0)
__global__ __launch_bounds__(256) void prep_wf_kernel(
    const float* __restrict__ Wf, ushort_t* __restrict__ Wfc)
{
    int idx = blockIdx.x * 256 + threadIdx.x;   // 8192
    if (idx >= 8192) return;
    int e = idx & 7;
    int lane = (idx >> 3) & 63;
    int nf = (idx >> 9) & 1;
    int w8 = idx >> 10;
    int n = w8 * 32 + nf * 16 + (lane & 15);
    int k = (lane >> 4) * 8 + e;
    Wfc[idx] = (k < FEAT) ? f2bf(Wf[k * HDIM + n]) : (ushort_t)0;
}

// ---------------- node init via MFMA: xb = fp8(LN(silu(emb[z] + feat@Wf + bf)))
__global__ __launch_bounds__(512, 4) void node_init_kernel(
    const int* __restrict__ z, const float* __restrict__ feat,
    const float* __restrict__ emb, const ushort_t* __restrict__ Wfc,
    const float* __restrict__ bfv, const float* __restrict__ g0,
    const float* __restrict__ b0, void* __restrict__ xb)
{
    __shared__ ushort_t sA[64][256];
    __shared__ float sGB[2][HDIM];
    const int tid = threadIdx.x;
    const int m0 = blockIdx.x * 64;
    const int lane = tid & 63;
    const int w = tid >> 6;
    const int lg = lane >> 4, ll = lane & 15;
    const int cb = w * 32;

    if (tid < HDIM) sGB[0][tid] = g0[tid];
    else sGB[1][tid - HDIM] = b0[tid - HDIM];

    f32x4 bvv[2];
    #pragma unroll
    for (int nf = 0; nf < 2; ++nf)
        bvv[nf] = *(const f32x4*)&bfv[cb + nf * 16 + lg * 4];

    bf16x8 wf[2];
    wf[0] = *(const bf16x8*)(Wfc + w * 1024 + lane * 8);
    wf[1] = *(const bf16x8*)(Wfc + w * 1024 + 512 + lane * 8);

    bf16x8 af[4];
    #pragma unroll
    for (int m = 0; m < 4; ++m) {
        int gr = m0 + m * 16 + ll;
        bf16x8 t = {};
        if (lg == 0) {
            #pragma unroll
            for (int j = 0; j < 8; ++j) t[j] = (short)f2bf(feat[gr * FEAT + j]);
        } else if (lg == 1) {
            t[0] = (short)f2bf(feat[gr * FEAT + 8]);
            t[1] = (short)f2bf(feat[gr * FEAT + 9]);
        }
        af[m] = t;
    }

    f32x4 acc[4][2] = {};
    #pragma unroll
    for (int m = 0; m < 4; ++m)
        #pragma unroll
        for (int nf = 0; nf < 2; ++nf)
            acc[m][nf] = __builtin_amdgcn_mfma_f32_16x16x32_bf16(
                wf[nf], af[m], acc[m][nf], 0, 0, 0);

    #pragma unroll
    for (int m = 0; m < 4; ++m) {
        int r = m * 16 + ll, rx = r & 7;
        int zi = z[m0 + r];
        #pragma unroll
        for (int nf = 0; nf < 2; ++nf) {
            int n0 = cb + nf * 16 + lg * 4;
            f32x4 ev = *(const f32x4*)&emb[(size_t)zi * HDIM + n0];
            int chunk = ((cb + nf * 16) >> 3) + (lg >> 1);
            int celloff = ((chunk ^ rx) << 3) + (lg & 1) * 4;
            ushort4 o;
            o.x = f2bf(silu_f(acc[m][nf][0] + ev[0] + bvv[nf][0]));
            o.y = f2bf(silu_f(acc[m][nf][1] + ev[1] + bvv[nf][1]));
            o.z = f2bf(silu_f(acc[m][nf][2] + ev[2] + bvv[nf][2]));
            o.w = f2bf(silu_f(acc[m][nf][3] + ev[3] + bvv[nf][3]));
            *(ushort4*)&sA[r][celloff] = o;
        }
    }
    __syncthreads();

    {
        int rr = tid >> 3, kk = tid & 7;
        int rot = (kk + rr) & 7;
        u16x8 v8[4];
        float s = 0.f, q = 0.f;
        #pragma unroll
        for (int i = 0; i < 4; ++i) {
            int slot = rot + 8 * i;
            v8[i] = *(const u16x8*)&sA[rr][slot << 3];
            #pragma unroll
            for (int j = 0; j < 8; ++j) {
                float v = bf2f(v8[i][j]);
                s += v; q += v * v;
            }
        }
        #pragma unroll
        for (int o = 1; o < 8; o <<= 1) {
            s += __shfl_xor(s, o, 64);
            q += __shfl_xor(q, o, 64);
        }
        float mu = s * (1.0f / HDIM);
        float var = q * (1.0f / HDIM) - mu * mu;
        float rs = rsqrtf(var + 1e-5f);
        size_t rows = ((size_t)(m0 + rr)) << XROW_SHIFT;
        #pragma unroll
        for (int i = 0; i < 4; ++i) {
            int slot = rot + 8 * i;
            int chunk = slot ^ (rr & 7);
            float ov[8];
            #pragma unroll
            for (int j = 0; j < 8; ++j)
                ov[j] = (bf2f(v8[i][j]) - mu) * rs * sGB[0][chunk * 8 + j]
                        + sGB[1][chunk * 8 + j];
            x8_store(xb, rows + slot, ov);
        }
    }
}

__global__ __launch_bounds__(256) void batch_out_kernel(
    const int* __restrict__ batch, float* __restrict__ out)
{
    int i = blockIdx.x * 256 + threadIdx.x;
    if (i < NN) out[i] = (float)batch[i];
}

// ---------------- CSR build
__global__ __launch_bounds__(256) void hist_kernel(const int* __restrict__ ei, int* __restrict__ deg)
{
    int i = blockIdx.x * 256 + threadIdx.x;
    if (i < EE) atomicAdd(&deg[ei[EE + i]], 1);
}

__global__ __launch_bounds__(256) void scan_blocks_kernel(
    const int* __restrict__ deg, int* __restrict__ off, int* __restrict__ psum)
{
    int blk = blockIdx.x, t = threadIdx.x;
    int base = blk * 1024 + t * 4;
    int v[4];
    #pragma unroll
    for (int i = 0; i < 4; ++i) v[i] = (base + i < NN) ? deg[base + i] : 0;
    int s = v[0] + v[1] + v[2] + v[3];
    int lane = t & 63, w = t >> 6;
    int ps = s;
    #pragma unroll
    for (int o = 1; o < 64; o <<= 1) { int u = __shfl_up(ps, o, 64); if (lane >= o) ps += u; }
    __shared__ int wt[4];
    if (lane == 63) wt[w] = ps;
    __syncthreads();
    int wbase = 0;
    for (int k = 0; k < w; ++k) wbase += wt[k];
    int run = wbase + ps - s;
    #pragma unroll
    for (int i = 0; i < 4; ++i) {
        if (base + i < NN) off[base + i] = run;
        run += v[i];
    }
    if (t == 255) psum[blk] = wbase + ps;
}

__global__ __launch_bounds__(256) void scan_top_kernel(int* __restrict__ psum, int nb)
{
    int t = threadIdx.x;
    int v = (t < nb) ? psum[t] : 0;
    int lane = t & 63, w = t >> 6;
    int ps = v;
    #pragma unroll
    for (int o = 1; o < 64; o <<= 1) { int u = __shfl_up(ps, o, 64); if (lane >= o) ps += u; }
    __shared__ int wt[4];
    if (lane == 63) wt[w] = ps;
    __syncthreads();
    int wbase = 0;
    for (int k = 0; k < w; ++k) wbase += wt[k];
    if (t < nb) psum[t] = wbase + ps - v;
}

__global__ __launch_bounds__(256) void scan_add_kernel(
    int* __restrict__ off, const int* __restrict__ psum, int* __restrict__ cursor)
{
    int i = blockIdx.x * 256 + threadIdx.x;
    if (i < NN) {
        int o = off[i] + psum[i >> 10];
        off[i] = o;
        cursor[i] = o;
        if (i == NN - 1) off[NN] = EE;
    }
}

__global__ __launch_bounds__(256) void scatter_kernel(
    const int* __restrict__ ei, const float* __restrict__ ea,
    int* __restrict__ cursor, int* __restrict__ srcs, float4* __restrict__ eaf)
{
    int i = blockIdx.x * 256 + threadIdx.x;
    if (i < EE) {
        int dst = ei[EE + i];
        int pos = atomicAdd(&cursor[dst], 1);
        srcs[pos] = ei[i];
        eaf[pos] = ((const float4*)ea)[i];
    }
}

// ---------------- edge MLP (layer-invariant): e = silu(eaf@We + be), CSR order (fp8/bf16)
__global__ __launch_bounds__(256) void edge_mlp_kernel(
    const float4* __restrict__ eaf, const float* __restrict__ We,
    const float* __restrict__ be, void* __restrict__ eout)
{
    int p = (blockIdx.x * 256 + threadIdx.x) >> 5;
    if (p >= EE) return;
    int nl = threadIdx.x & 31, c0 = nl * 8;
    float4 av = eaf[p];
    float v[8];
    #pragma unroll
    for (int j = 0; j < 8; ++j) {
        float t = be[c0 + j] + av.x * We[c0 + j] + av.y * We[HDIM + c0 + j]
                + av.z * We[2 * HDIM + c0 + j] + av.w * We[3 * HDIM + c0 + j];
        v[j] = silu_f(t);
    }
    x8_store(eout, ((size_t)p << 5) + nl, v);
}

// ---------------- weights: W[l][k][n] f32 -> chunk-major per-wave (8 col-waves) bf16
__global__ __launch_bounds__(256) void prep_w_kernel(
    const float* __restrict__ W1, const float* __restrict__ W2,
    ushort_t* __restrict__ Wc1, ushort_t* __restrict__ Wc2)
{
    int idx = blockIdx.x * 256 + threadIdx.x;   // 2 * 4 * 65536
    int which = idx >> 18;
    int rem = idx & 0x3FFFF;
    int l = rem >> 16;
    int t = rem & 0xFFFF;
    int e = t & 7;
    int lane = (t >> 3) & 63;
    int nf = (t >> 9) & 1;
    int w8 = (t >> 10) & 7;
    int c = (t >> 13) & 7;
    int n = w8 * 32 + nf * 16 + (lane & 15);
    int k = c * 32 + (lane >> 4) * 8 + e;
    const float* W = which ? W2 : W1;
    ushort_t* Wc = which ? Wc2 : Wc1;
    Wc[rem] = f2bf(W[l * 65536 + k * 256 + n]);
}

// ---------------- aggregation: U = fp8(x_self + sum relu(x[src]+e)); 32-lane groups
template<int USE_E>
__global__ __launch_bounds__(256) void agg_kernel(
    const int* __restrict__ off, const int* __restrict__ srcs,
    const void* __restrict__ eprec, const float4* __restrict__ eaf,
    const float* __restrict__ We, const float* __restrict__ be,
    const void* __restrict__ xin, void* __restrict__ U)
{
    const int gstride = (gridDim.x * 256) >> 5;
    const int gid0 = (blockIdx.x * 256 + threadIdx.x) >> 5;
    const int nl = threadIdx.x & 31, c0 = nl * 8;
    float wv[4][8], bev[8];
    if (!USE_E) {
        #pragma unroll
        for (int r4 = 0; r4 < 4; ++r4)
            #pragma unroll
            for (int j = 0; j < 8; ++j) wv[r4][j] = We[r4 * HDIM + c0 + j];
        #pragma unroll
        for (int j = 0; j < 8; ++j) bev[j] = be[c0 + j];
    }

    for (int n = gid0; n < NN; n += gstride) {
        float acc[8];
        x8_load(xin, (((size_t)n) << XROW_SHIFT) + (nl ^ (n & 7)), acc);
        int beg = off[n], end = off[n + 1];
        if (USE_E) {
            for (int p = beg; p < end; ++p) {
                int src = srcs[p];
                float xg[8], ev[8];
                x8_load(xin, (((size_t)src) << XROW_SHIFT) + (nl ^ (src & 7)), xg);
                x8_load(eprec, ((size_t)p << 5) + nl, ev);
                #pragma unroll
                for (int j = 0; j < 8; ++j)
                    acc[j] += fmaxf(xg[j] + ev[j], 0.f);
            }
        } else {
            for (int p = beg; p < end; ++p) {
                int src = srcs[p];
                float4 av = eaf[p];
                float xg[8];
                x8_load(xin, (((size_t)src) << XROW_SHIFT) + (nl ^ (src & 7)), xg);
                #pragma unroll
                for (int j = 0; j < 8; ++j) {
                    float e = silu_f(bev[j] + av.x * wv[0][j] + av.y * wv[1][j]
                                            + av.z * wv[2][j] + av.w * wv[3][j]);
                    acc[j] += fmaxf(xg[j] + e, 0.f);
                }
            }
        }
        x8_store(U, (((size_t)n) << XROW_SHIFT) + (nl ^ (n & 7)), acc);
    }
}

// ---------------- MLP + LN: out = LN(xin + (silu(U@W1+b1))@W2 + b2); all x/U fp8
template<int LAST>
__global__ __launch_bounds__(512, 4) void mlp_kernel(
    const void* __restrict__ U, const ushort_t* __restrict__ Wc1,
    const ushort_t* __restrict__ Wc2, const float* __restrict__ b1,
    const float* __restrict__ b2, const float* __restrict__ lng,
    const float* __restrict__ lnb, const void* __restrict__ xin,
    void* __restrict__ xout, float* __restrict__ xf32)
{
    __shared__ ushort_t sA[64][256];     // 32KB: U -> t -> h (swizzled cells)
    __shared__ float sGB[2][HDIM];       // 2KB gamma/beta
    const int tid = threadIdx.x;
    const int m0 = blockIdx.x * 64;
    const int lane = tid & 63;
    const int w = tid >> 6;
    const int lg = lane >> 4, ll = lane & 15;
    const int cb = w * 32;

    if (tid < HDIM) sGB[0][tid] = lng[tid];
    else sGB[1][tid - HDIM] = lnb[tid - HDIM];

    f32x4 bv1v[2], bv2v[2];
    #pragma unroll
    for (int nf = 0; nf < 2; ++nf) {
        int nb = cb + nf * 16 + lg * 4;
        bv1v[nf] = *(const f32x4*)&b1[nb];
        bv2v[nf] = *(const f32x4*)&b2[nb];
    }

    // ---- stage U tile: fp8 global (pre-swizzled slots) -> bf16 sA cells
    {
        #pragma unroll
        for (int it = 0; it < 4; ++it) {
            int idx = tid + it * 512;            // row*32 + slot
            float f[8];
            x8_load(U, (((size_t)m0) << XROW_SHIFT) + idx, f);
            u16x8 o;
            #pragma unroll
            for (int j = 0; j < 8; ++j) o[j] = f2bf(f[j]);
            *(u16x8*)((ushort_t*)sA + (idx << 3)) = o;
        }
    }
    __syncthreads();

    f32x4 acc[4][2] = {};
    const ushort_t* wp1 = Wc1 + w * 1024 + lane * 8;
    const ushort_t* wp2 = Wc2 + w * 1024 + lane * 8;
    bf16x8 wbuf[2][2];
    wbuf[0][0] = *(const bf16x8*)(wp1);
    wbuf[0][1] = *(const bf16x8*)(wp1 + 512);

    // ---- GEMM1 (reg prefetch; last iter prefetches W2 chunk0); W as A-operand
    #pragma unroll
    for (int p = 0; p < 8; ++p) {
        const ushort_t* nsrc = (p < 7) ? (wp1 + (p + 1) * 8192) : wp2;
        wbuf[(p + 1) & 1][0] = *(const bf16x8*)(nsrc);
        wbuf[(p + 1) & 1][1] = *(const bf16x8*)(nsrc + 512);
        bf16x8 af[4];
        #pragma unroll
        for (int m = 0; m < 4; ++m) {
            int r = m * 16 + ll;
            af[m] = *(const bf16x8*)&sA[r][(((p * 4 + lg) ^ (r & 7)) << 3)];
        }
        #pragma unroll
        for (int m = 0; m < 4; ++m)
            #pragma unroll
            for (int nf = 0; nf < 2; ++nf)
                acc[m][nf] = __builtin_amdgcn_mfma_f32_16x16x32_bf16(
                    wbuf[p & 1][nf], af[m], acc[m][nf], 0, 0, 0);
    }
    __syncthreads();   // all waves done reading sA(U)

    // ---- t = silu(acc + b1) -> sA via ds_write_b64; reset acc
    #pragma unroll
    for (int m = 0; m < 4; ++m) {
        int r = m * 16 + ll, rx = r & 7;
        #pragma unroll
        for (int nf = 0; nf < 2; ++nf) {
            int chunk = ((cb + nf * 16) >> 3) + (lg >> 1);
            int celloff = ((chunk ^ rx) << 3) + (lg & 1) * 4;
            ushort4 o;
            o.x = f2bf(silu_f(acc[m][nf][0] + bv1v[nf][0]));
            o.y = f2bf(silu_f(acc[m][nf][1] + bv1v[nf][1]));
            o.z = f2bf(silu_f(acc[m][nf][2] + bv1v[nf][2]));
            o.w = f2bf(silu_f(acc[m][nf][3] + bv1v[nf][3]));
            *(ushort4*)&sA[r][celloff] = o;
            acc[m][nf][0] = 0.f; acc[m][nf][1] = 0.f;
            acc[m][nf][2] = 0.f; acc[m][nf][3] = 0.f;
        }
    }
    __syncthreads();   // t visible

    // ---- GEMM2
    #pragma unroll
    for (int p = 0; p < 8; ++p) {
        if (p < 7) {
            wbuf[(p + 1) & 1][0] = *(const bf16x8*)(wp2 + (p + 1) * 8192);
            wbuf[(p + 1) & 1][1] = *(const bf16x8*)(wp2 + (p + 1) * 8192 + 512);
        }
        bf16x8 af[4];
        #pragma unroll
        for (int m = 0; m < 4; ++m) {
            int r = m * 16 + ll;
            af[m] = *(const bf16x8*)&sA[r][(((p * 4 + lg) ^ (r & 7)) << 3)];
        }
        #pragma unroll
        for (int m = 0; m < 4; ++m)
            #pragma unroll
            for (int nf = 0; nf < 2; ++nf)
                acc[m][nf] = __builtin_amdgcn_mfma_f32_16x16x32_bf16(
                    wbuf[p & 1][nf], af[m], acc[m][nf], 0, 0, 0);
    }
    __syncthreads();   // all waves done reading sA(t)

    // ---- h = acc + b2 -> sA cells (ds_write_b64)
    #pragma unroll
    for (int m = 0; m < 4; ++m) {
        int r = m * 16 + ll, rx = r & 7;
        #pragma unroll
        for (int nf = 0; nf < 2; ++nf) {
            int chunk = ((cb + nf * 16) >> 3) + (lg >> 1);
            int celloff = ((chunk ^ rx) << 3) + (lg & 1) * 4;
            ushort4 o;
            o.x = f2bf(acc[m][nf][0] + bv2v[nf][0]);
            o.y = f2bf(acc[m][nf][1] + bv2v[nf][1]);
            o.z = f2bf(acc[m][nf][2] + bv2v[nf][2]);
            o.w = f2bf(acc[m][nf][3] + bv2v[nf][3]);
            *(ushort4*)&sA[r][celloff] = o;
        }
    }
    __syncthreads();   // h visible

    // ---- row-pass LN: 8 thr/row, rotation swizzle; residual x from global (fp8)
    {
        int rr = tid >> 3, kk = tid & 7;
        int rot = (kk + rr) & 7;
        size_t rows = ((size_t)(m0 + rr)) << XROW_SHIFT;
        float vv[4][8];
        float s = 0.f, q = 0.f;
        #pragma unroll
        for (int i = 0; i < 4; ++i) {
            int slot = rot + 8 * i;
            u16x8 h8 = *(const u16x8*)&sA[rr][slot << 3];
            float x8[8];
            x8_load(xin, rows + slot, x8);
            #pragma unroll
            for (int j = 0; j < 8; ++j) {
                float v = bf2f(h8[j]) + x8[j];
                vv[i][j] = v;
                s += v; q += v * v;
            }
        }
        #pragma unroll
        for (int o = 1; o < 8; o <<= 1) {
            s += __shfl_xor(s, o, 64);
            q += __shfl_xor(q, o, 64);
        }
        float mu = s * (1.0f / HDIM);
        float var = q * (1.0f / HDIM) - mu * mu;
        float rs = rsqrtf(var + 1e-5f);
        #pragma unroll
        for (int i = 0; i < 4; ++i) {
            int slot = rot + 8 * i;
            int chunk = slot ^ (rr & 7);
            if (LAST) {
                float* xrow = xf32 + (((size_t)(m0 + rr)) << 8);
                f32x4 o0, o1;
                #pragma unroll
                for (int j = 0; j < 4; ++j) {
                    o0[j] = (vv[i][j] - mu) * rs * sGB[0][chunk * 8 + j]
                            + sGB[1][chunk * 8 + j];
                    o1[j] = (vv[i][4 + j] - mu) * rs * sGB[0][chunk * 8 + 4 + j]
                            + sGB[1][chunk * 8 + 4 + j];
                }
                *(f32x4*)&xrow[chunk * 8] = o0;
                *(f32x4*)&xrow[chunk * 8 + 4] = o1;
            } else {
                float ov[8];
                #pragma unroll
                for (int j = 0; j < 8; ++j)
                    ov[j] = (vv[i][j] - mu) * rs * sGB[0][chunk * 8 + j]
                            + sGB[1][chunk * 8 + j];
                x8_store(xout, rows + slot, ov);
            }
        }
    }
}

extern "C" void kernel_launch(void* const* d_in, const int* in_sizes, int n_in,
                              void* d_out, int out_size, void* d_ws, size_t ws_size,
                              hipStream_t stream)
{
    const int*   z    = (const int*)d_in[0];
    const float* feat = (const float*)d_in[1];
    const int*   ei   = (const int*)d_in[2];
    const float* ea   = (const float*)d_in[3];
    const int*   batch= (const int*)d_in[4];
    const float* emb  = (const float*)d_in[5];
    const float* Wf   = (const float*)d_in[6];
    const float* bfv  = (const float*)d_in[7];
    const float* g0   = (const float*)d_in[8];
    const float* b0   = (const float*)d_in[9];
    const float* We   = (const float*)d_in[10];
    const float* be   = (const float*)d_in[11];
    const float* W1   = (const float*)d_in[12];
    const float* b1   = (const float*)d_in[13];
    const float* W2   = (const float*)d_in[14];
    const float* b2   = (const float*)d_in[15];
    const float* lng  = (const float*)d_in[16];
    const float* lnb  = (const float*)d_in[17];

    float* x    = (float*)d_out;
    float* outb = (float*)d_out + (size_t)NN * HDIM;

#if HAVE_FP8
    const size_t XBYTES = (size_t)NN * 256;           // fp8: 1B/elem
    const size_t EBYTES = (size_t)EE * 256;
#else
    const size_t XBYTES = (size_t)NN * 512;           // bf16: 2B/elem
    const size_t EBYTES = (size_t)EE * 512;
#endif
    char* ws = (char*)d_ws;
    size_t o = 0;
    void* xb0 = (void*)(ws + o); o += XBYTES;
    void* xb1 = (void*)(ws + o); o += XBYTES;
    void* Ubuf = (void*)(ws + o); o += XBYTES;
    float4* eaf = (float4*)(ws + o); o += (size_t)EE * 16;
    int* srcs = (int*)(ws + o); o += (size_t)EE * 4;
    int* off = (int*)(ws + o); o += (size_t)(NN + 4) * 4;
    int* cursor = (int*)(ws + o); o += (size_t)NN * 4;
    int* deg = (int*)(ws + o); o += (size_t)NN * 4;
    int* psum = (int*)(ws + o); o += 1024;
    ushort_t* Wc1 = (ushort_t*)(ws + o); o += 524288;
    ushort_t* Wc2 = (ushort_t*)(ws + o); o += 524288;
    ushort_t* Wfc = (ushort_t*)(ws + o); o += 16384;
    void* eprec = (void*)(ws + o); o += EBYTES;
    const int use_e = (ws_size >= o) ? 1 : 0;

    prep_w_kernel<<<2048, 256, 0, stream>>>(W1, W2, Wc1, Wc2);
    prep_wf_kernel<<<32, 256, 0, stream>>>(Wf, Wfc);
    batch_out_kernel<<<782, 256, 0, stream>>>(batch, outb);
    node_init_kernel<<<NN / 64, 512, 0, stream>>>(z, feat, emb, Wfc, bfv, g0, b0, xb0);

    hipMemsetAsync(deg, 0, NN * sizeof(int), stream);
    hist_kernel<<<1563, 256, 0, stream>>>(ei, deg);
    scan_blocks_kernel<<<196, 256, 0, stream>>>(deg, off, psum);
    scan_top_kernel<<<1, 256, 0, stream>>>(psum, 196);
    scan_add_kernel<<<782, 256, 0, stream>>>(off, psum, cursor);
    scatter_kernel<<<1563, 256, 0, stream>>>(ei, ea, cursor, srcs, eaf);
    if (use_e)
        edge_mlp_kernel<<<EE / 8, 256, 0, stream>>>(eaf, We, be, eprec);

    // x ping-pong between xb0/xb1 (fp8); U (fp8) in its own buffer.
    void* xbuf[2] = {xb0, xb1};
    for (int l = 0; l < LL; ++l) {
        void* xin  = xbuf[l & 1];
        void* xout = xbuf[(l + 1) & 1];
        if (use_e)
            agg_kernel<1><<<2048, 256, 0, stream>>>(off, srcs, eprec, eaf, We, be, xin, Ubuf);
        else
            agg_kernel<0><<<2048, 256, 0, stream>>>(off, srcs, eprec, eaf, We, be, xin, Ubuf);
        if (l == LL - 1) {
            mlp_kernel<1><<<NN / 64, 512, 0, stream>>>(
                Ubuf, Wc1 + l * 65536, Wc2 + l * 65536, b1 + l * HDIM, b2 + l * HDIM,
                lng + l * HDIM, lnb + l * HDIM, xin, xout, x);
        } else {
            mlp_kernel<0><<<NN / 64, 512, 0, stream>>>(
                Ubuf, Wc1 + l * 65536, Wc2 + l * 65536, b1 + l * HDIM, b2 + l * HDIM,
                lng + l * HDIM, lnb + l * HDIM, xin, xout, nullptr);
        }
    }
}

// Round 19
// 712.644 us; speedup vs baseline: 1.5363x; 1.1059x over previous
//
#include <hip/hip_runtime.h>
#include <hip/hip_bf16.h>

#define NN 200000
#define EE 400000
#define HDIM 256
#define LL 4
#define FEAT 10

typedef unsigned short ushort_t;
typedef unsigned char uchar_t;
typedef __attribute__((ext_vector_type(8))) short bf16x8;
typedef __attribute__((ext_vector_type(8))) unsigned short u16x8;
typedef __attribute__((ext_vector_type(2))) float f32x2;
typedef __attribute__((ext_vector_type(4))) float f32x4;
typedef __attribute__((ext_vector_type(4))) unsigned int u32x4;

__device__ inline ushort_t f2bf(float f) {
    unsigned int u = __builtin_bit_cast(unsigned int, f);
    return (ushort_t)((u + 0x7fffu + ((u >> 16) & 1u)) >> 16);
}
__device__ inline float bf2f(ushort_t s) {
    unsigned int u = ((unsigned int)s) << 16;
    return __builtin_bit_cast(float, u);
}
__device__ inline float silu_f(float v) { return v / (1.0f + __expf(-v)); }

// ---- x / U / e storage: fp8 e4m3 (8 cols -> uint2 = 8 bytes).
// Row layout: slot s (8-col granule) holds true 8-col chunk s ^ (n&7), s in [0,32).
__device__ inline void x8_load(const void* base, size_t idx, float* f) {
    uint2 v = ((const uint2*)base)[idx];
    f32x2 a0 = __builtin_amdgcn_cvt_pk_f32_fp8((int)v.x, false);
    f32x2 a1 = __builtin_amdgcn_cvt_pk_f32_fp8((int)v.x, true);
    f32x2 a2 = __builtin_amdgcn_cvt_pk_f32_fp8((int)v.y, false);
    f32x2 a3 = __builtin_amdgcn_cvt_pk_f32_fp8((int)v.y, true);
    f[0]=a0[0]; f[1]=a0[1]; f[2]=a1[0]; f[3]=a1[1];
    f[4]=a2[0]; f[5]=a2[1]; f[6]=a3[0]; f[7]=a3[1];
}
__device__ inline void x8_store(void* base, size_t idx, const float* f) {
    int t0 = __builtin_amdgcn_cvt_pk_fp8_f32(f[0], f[1], 0, false);
    t0 = __builtin_amdgcn_cvt_pk_fp8_f32(f[2], f[3], t0, true);
    int t1 = __builtin_amdgcn_cvt_pk_fp8_f32(f[4], f[5], 0, false);
    t1 = __builtin_amdgcn_cvt_pk_fp8_f32(f[6], f[7], t1, true);
    uint2 o; o.x = (unsigned int)t0; o.y = (unsigned int)t1;
    ((uint2*)base)[idx] = o;
}

// ---------------- Wf pre-pack: A-operand fragment layout (bf16), single K=32 chunk
__global__ __launch_bounds__(256) void prep_wf_kernel(
    const float* __restrict__ Wf, ushort_t* __restrict__ Wfc)
{
    int idx = blockIdx.x * 256 + threadIdx.x;   // 8192
    if (idx >= 8192) return;
    int e = idx & 7;
    int lane = (idx >> 3) & 63;
    int nf = (idx >> 9) & 1;
    int w8 = idx >> 10;
    int n = w8 * 32 + nf * 16 + (lane & 15);
    int k = (lane >> 4) * 8 + e;
    Wfc[idx] = (k < FEAT) ? f2bf(Wf[k * HDIM + n]) : (ushort_t)0;
}

// ---------------- node init via MFMA (bf16): xb = fp8(LN(silu(emb[z] + feat@Wf + bf)))
__global__ __launch_bounds__(512, 4) void node_init_kernel(
    const int* __restrict__ z, const float* __restrict__ feat,
    const float* __restrict__ emb, const ushort_t* __restrict__ Wfc,
    const float* __restrict__ bfv, const float* __restrict__ g0,
    const float* __restrict__ b0, void* __restrict__ xb)
{
    __shared__ ushort_t sA[64][256];
    __shared__ float sGB[2][HDIM];
    const int tid = threadIdx.x;
    const int m0 = blockIdx.x * 64;
    const int lane = tid & 63;
    const int w = tid >> 6;
    const int lg = lane >> 4, ll = lane & 15;
    const int cb = w * 32;

    if (tid < HDIM) sGB[0][tid] = g0[tid];
    else sGB[1][tid - HDIM] = b0[tid - HDIM];

    f32x4 bvv[2];
    #pragma unroll
    for (int nf = 0; nf < 2; ++nf)
        bvv[nf] = *(const f32x4*)&bfv[cb + nf * 16 + lg * 4];

    bf16x8 wf[2];
    wf[0] = *(const bf16x8*)(Wfc + w * 1024 + lane * 8);
    wf[1] = *(const bf16x8*)(Wfc + w * 1024 + 512 + lane * 8);

    bf16x8 af[4];
    #pragma unroll
    for (int m = 0; m < 4; ++m) {
        int gr = m0 + m * 16 + ll;
        bf16x8 t = {};
        if (lg == 0) {
            #pragma unroll
            for (int j = 0; j < 8; ++j) t[j] = (short)f2bf(feat[gr * FEAT + j]);
        } else if (lg == 1) {
            t[0] = (short)f2bf(feat[gr * FEAT + 8]);
            t[1] = (short)f2bf(feat[gr * FEAT + 9]);
        }
        af[m] = t;
    }

    f32x4 acc[4][2] = {};
    #pragma unroll
    for (int m = 0; m < 4; ++m)
        #pragma unroll
        for (int nf = 0; nf < 2; ++nf)
            acc[m][nf] = __builtin_amdgcn_mfma_f32_16x16x32_bf16(
                wf[nf], af[m], acc[m][nf], 0, 0, 0);

    #pragma unroll
    for (int m = 0; m < 4; ++m) {
        int r = m * 16 + ll, rx = r & 7;
        int zi = z[m0 + r];
        #pragma unroll
        for (int nf = 0; nf < 2; ++nf) {
            int n0 = cb + nf * 16 + lg * 4;
            f32x4 ev = *(const f32x4*)&emb[(size_t)zi * HDIM + n0];
            int chunk = ((cb + nf * 16) >> 3) + (lg >> 1);
            int celloff = ((chunk ^ rx) << 3) + (lg & 1) * 4;
            ushort4 o;
            o.x = f2bf(silu_f(acc[m][nf][0] + ev[0] + bvv[nf][0]));
            o.y = f2bf(silu_f(acc[m][nf][1] + ev[1] + bvv[nf][1]));
            o.z = f2bf(silu_f(acc[m][nf][2] + ev[2] + bvv[nf][2]));
            o.w = f2bf(silu_f(acc[m][nf][3] + ev[3] + bvv[nf][3]));
            *(ushort4*)&sA[r][celloff] = o;
        }
    }
    __syncthreads();

    {
        int rr = tid >> 3, kk = tid & 7;
        int rot = (kk + rr) & 7;
        u16x8 v8[4];
        float s = 0.f, q = 0.f;
        #pragma unroll
        for (int i = 0; i < 4; ++i) {
            int slot = rot + 8 * i;
            v8[i] = *(const u16x8*)&sA[rr][slot << 3];
            #pragma unroll
            for (int j = 0; j < 8; ++j) {
                float v = bf2f(v8[i][j]);
                s += v; q += v * v;
            }
        }
        #pragma unroll
        for (int o = 1; o < 8; o <<= 1) {
            s += __shfl_xor(s, o, 64);
            q += __shfl_xor(q, o, 64);
        }
        float mu = s * (1.0f / HDIM);
        float var = q * (1.0f / HDIM) - mu * mu;
        float rs = rsqrtf(var + 1e-5f);
        size_t rows = ((size_t)(m0 + rr)) << 5;
        #pragma unroll
        for (int i = 0; i < 4; ++i) {
            int slot = rot + 8 * i;
            int chunk = slot ^ (rr & 7);
            float ov[8];
            #pragma unroll
            for (int j = 0; j < 8; ++j)
                ov[j] = (bf2f(v8[i][j]) - mu) * rs * sGB[0][chunk * 8 + j]
                        + sGB[1][chunk * 8 + j];
            x8_store(xb, rows + slot, ov);
        }
    }
}

__global__ __launch_bounds__(256) void batch_out_kernel(
    const int* __restrict__ batch, float* __restrict__ out)
{
    int i = blockIdx.x * 256 + threadIdx.x;
    if (i < NN) out[i] = (float)batch[i];
}

// ---------------- CSR build
__global__ __launch_bounds__(256) void hist_kernel(const int* __restrict__ ei, int* __restrict__ deg)
{
    int i = blockIdx.x * 256 + threadIdx.x;
    if (i < EE) atomicAdd(&deg[ei[EE + i]], 1);
}

__global__ __launch_bounds__(256) void scan_blocks_kernel(
    const int* __restrict__ deg, int* __restrict__ off, int* __restrict__ psum)
{
    int blk = blockIdx.x, t = threadIdx.x;
    int base = blk * 1024 + t * 4;
    int v[4];
    #pragma unroll
    for (int i = 0; i < 4; ++i) v[i] = (base + i < NN) ? deg[base + i] : 0;
    int s = v[0] + v[1] + v[2] + v[3];
    int lane = t & 63, w = t >> 6;
    int ps = s;
    #pragma unroll
    for (int o = 1; o < 64; o <<= 1) { int u = __shfl_up(ps, o, 64); if (lane >= o) ps += u; }
    __shared__ int wt[4];
    if (lane == 63) wt[w] = ps;
    __syncthreads();
    int wbase = 0;
    for (int k = 0; k < w; ++k) wbase += wt[k];
    int run = wbase + ps - s;
    #pragma unroll
    for (int i = 0; i < 4; ++i) {
        if (base + i < NN) off[base + i] = run;
        run += v[i];
    }
    if (t == 255) psum[blk] = wbase + ps;
}

__global__ __launch_bounds__(256) void scan_top_kernel(int* __restrict__ psum, int nb)
{
    int t = threadIdx.x;
    int v = (t < nb) ? psum[t] : 0;
    int lane = t & 63, w = t >> 6;
    int ps = v;
    #pragma unroll
    for (int o = 1; o < 64; o <<= 1) { int u = __shfl_up(ps, o, 64); if (lane >= o) ps += u; }
    __shared__ int wt[4];
    if (lane == 63) wt[w] = ps;
    __syncthreads();
    int wbase = 0;
    for (int k = 0; k < w; ++k) wbase += wt[k];
    if (t < nb) psum[t] = wbase + ps - v;
}

__global__ __launch_bounds__(256) void scan_add_kernel(
    int* __restrict__ off, const int* __restrict__ psum, int* __restrict__ cursor)
{
    int i = blockIdx.x * 256 + threadIdx.x;
    if (i < NN) {
        int o = off[i] + psum[i >> 10];
        off[i] = o;
        cursor[i] = o;
        if (i == NN - 1) off[NN] = EE;
    }
}

__global__ __launch_bounds__(256) void scatter_kernel(
    const int* __restrict__ ei, const float* __restrict__ ea,
    int* __restrict__ cursor, int* __restrict__ srcs, float4* __restrict__ eaf)
{
    int i = blockIdx.x * 256 + threadIdx.x;
    if (i < EE) {
        int dst = ei[EE + i];
        int pos = atomicAdd(&cursor[dst], 1);
        srcs[pos] = ei[i];
        eaf[pos] = ((const float4*)ea)[i];
    }
}

// ---------------- edge MLP (layer-invariant): e = fp8(silu(eaf@We + be)), CSR order
__global__ __launch_bounds__(256) void edge_mlp_kernel(
    const float4* __restrict__ eaf, const float* __restrict__ We,
    const float* __restrict__ be, void* __restrict__ eout)
{
    int p = (blockIdx.x * 256 + threadIdx.x) >> 5;
    if (p >= EE) return;
    int nl = threadIdx.x & 31, c0 = nl * 8;
    float4 av = eaf[p];
    float v[8];
    #pragma unroll
    for (int j = 0; j < 8; ++j) {
        float t = be[c0 + j] + av.x * We[c0 + j] + av.y * We[HDIM + c0 + j]
                + av.z * We[2 * HDIM + c0 + j] + av.w * We[3 * HDIM + c0 + j];
        v[j] = silu_f(t);
    }
    x8_store(eout, ((size_t)p << 5) + nl, v);
}

// ---------------- weights: W[l][k][n] f32 -> chunk-major per-wave fragment layout, fp8
// index bits: e(3) lane(6) nf(1) w8(3) c(3), per layer 65536 bytes.
__global__ __launch_bounds__(256) void prep_w_kernel(
    const float* __restrict__ W1, const float* __restrict__ W2,
    uchar_t* __restrict__ Wc1, uchar_t* __restrict__ Wc2)
{
    int idx = blockIdx.x * 256 + threadIdx.x;   // 2 * 4 * 65536
    int which = idx >> 18;
    int rem = idx & 0x3FFFF;
    int l = rem >> 16;
    int t = rem & 0xFFFF;
    int e = t & 7;
    int lane = (t >> 3) & 63;
    int nf = (t >> 9) & 1;
    int w8 = (t >> 10) & 7;
    int c = (t >> 13) & 7;
    int n = w8 * 32 + nf * 16 + (lane & 15);
    int k = c * 32 + (lane >> 4) * 8 + e;
    const float* W = which ? W2 : W1;
    float v = W[l * 65536 + k * 256 + n];
    uchar_t* Wc = which ? Wc2 : Wc1;
    int pk = __builtin_amdgcn_cvt_pk_fp8_f32(v, v, 0, false);
    Wc[rem] = (uchar_t)(pk & 0xFF);
}

// ---------------- aggregation: U = fp8(x_self + sum relu(x[src]+e)); 32-lane groups
template<int USE_E>
__global__ __launch_bounds__(256) void agg_kernel(
    const int* __restrict__ off, const int* __restrict__ srcs,
    const void* __restrict__ eprec, const float4* __restrict__ eaf,
    const float* __restrict__ We, const float* __restrict__ be,
    const void* __restrict__ xin, void* __restrict__ U)
{
    const int gstride = (gridDim.x * 256) >> 5;
    const int gid0 = (blockIdx.x * 256 + threadIdx.x) >> 5;
    const int nl = threadIdx.x & 31, c0 = nl * 8;
    float wv[4][8], bev[8];
    if (!USE_E) {
        #pragma unroll
        for (int r4 = 0; r4 < 4; ++r4)
            #pragma unroll
            for (int j = 0; j < 8; ++j) wv[r4][j] = We[r4 * HDIM + c0 + j];
        #pragma unroll
        for (int j = 0; j < 8; ++j) bev[j] = be[c0 + j];
    }

    for (int n = gid0; n < NN; n += gstride) {
        float acc[8];
        x8_load(xin, (((size_t)n) << 5) + (nl ^ (n & 7)), acc);
        int beg = off[n], end = off[n + 1];
        if (USE_E) {
            for (int p = beg; p < end; ++p) {
                int src = srcs[p];
                float xg[8], ev[8];
                x8_load(xin, (((size_t)src) << 5) + (nl ^ (src & 7)), xg);
                x8_load(eprec, ((size_t)p << 5) + nl, ev);
                #pragma unroll
                for (int j = 0; j < 8; ++j)
                    acc[j] += fmaxf(xg[j] + ev[j], 0.f);
            }
        } else {
            for (int p = beg; p < end; ++p) {
                int src = srcs[p];
                float4 av = eaf[p];
                float xg[8];
                x8_load(xin, (((size_t)src) << 5) + (nl ^ (src & 7)), xg);
                #pragma unroll
                for (int j = 0; j < 8; ++j) {
                    float e = silu_f(bev[j] + av.x * wv[0][j] + av.y * wv[1][j]
                                            + av.z * wv[2][j] + av.w * wv[3][j]);
                    acc[j] += fmaxf(xg[j] + e, 0.f);
                }
            }
        }
        x8_store(U, (((size_t)n) << 5) + (nl ^ (n & 7)), acc);
    }
}

// ---------------- MLP + LN, full fp8 GEMM path: fp8 LDS tile, fp8 weights, mfma_fp8_fp8
template<int LAST>
__global__ __launch_bounds__(512, 4) void mlp_kernel(
    const void* __restrict__ U, const uchar_t* __restrict__ Wc1,
    const uchar_t* __restrict__ Wc2, const float* __restrict__ b1,
    const float* __restrict__ b2, const float* __restrict__ lng,
    const float* __restrict__ lnb, const void* __restrict__ xin,
    void* __restrict__ xout, float* __restrict__ xf32)
{
    __shared__ uchar_t sF[64][256];      // 16KB fp8 cells: U -> t -> h
    __shared__ float sGB[2][HDIM];       // 2KB gamma/beta
    const int tid = threadIdx.x;
    const int m0 = blockIdx.x * 64;
    const int lane = tid & 63;
    const int w = tid >> 6;
    const int lg = lane >> 4, ll = lane & 15;
    const int cb = w * 32;

    if (tid < HDIM) sGB[0][tid] = lng[tid];
    else sGB[1][tid - HDIM] = lnb[tid - HDIM];

    f32x4 bv1v[2], bv2v[2];
    #pragma unroll
    for (int nf = 0; nf < 2; ++nf) {
        int nb = cb + nf * 16 + lg * 4;
        bv1v[nf] = *(const f32x4*)&b1[nb];
        bv2v[nf] = *(const f32x4*)&b2[nb];
    }

    // ---- stage U tile: pure 8B copy (fp8 global -> fp8 LDS, layout identical)
    {
        const uint2* Uq = (const uint2*)U + (((size_t)m0) << 5);
        uint2* sQ = (uint2*)&sF[0][0];
        #pragma unroll
        for (int it = 0; it < 4; ++it) {
            int idx = tid + it * 512;
            sQ[idx] = Uq[idx];
        }
    }
    __syncthreads();

    f32x4 acc[4][2] = {};
    const uchar_t* wp1 = Wc1 + w * 1024 + lane * 8;
    const uchar_t* wp2 = Wc2 + w * 1024 + lane * 8;
    long long wbuf[2][2];
    wbuf[0][0] = *(const long long*)(wp1);
    wbuf[0][1] = *(const long long*)(wp1 + 512);

    // ---- GEMM1 (fp8): reg prefetch; last iter prefetches W2 chunk0
    #pragma unroll
    for (int p = 0; p < 8; ++p) {
        const uchar_t* nsrc = (p < 7) ? (wp1 + (p + 1) * 8192) : wp2;
        wbuf[(p + 1) & 1][0] = *(const long long*)(nsrc);
        wbuf[(p + 1) & 1][1] = *(const long long*)(nsrc + 512);
        long long af[4];
        #pragma unroll
        for (int m = 0; m < 4; ++m) {
            int r = m * 16 + ll;
            af[m] = *(const long long*)&sF[r][(((p * 4 + lg) ^ (r & 7)) << 3)];
        }
        #pragma unroll
        for (int m = 0; m < 4; ++m)
            #pragma unroll
            for (int nf = 0; nf < 2; ++nf)
                acc[m][nf] = __builtin_amdgcn_mfma_f32_16x16x32_fp8_fp8(
                    wbuf[p & 1][nf], af[m], acc[m][nf], 0, 0, 0);
    }
    __syncthreads();   // all waves done reading sF(U)

    // ---- t = fp8(silu(acc + b1)) -> sF (4B packs); reset acc
    #pragma unroll
    for (int m = 0; m < 4; ++m) {
        int r = m * 16 + ll, rx = r & 7;
        #pragma unroll
        for (int nf = 0; nf < 2; ++nf) {
            int chunk = ((cb + nf * 16) >> 3) + (lg >> 1);
            int boff = ((chunk ^ rx) << 3) + (lg & 1) * 4;
            float v0 = silu_f(acc[m][nf][0] + bv1v[nf][0]);
            float v1 = silu_f(acc[m][nf][1] + bv1v[nf][1]);
            float v2 = silu_f(acc[m][nf][2] + bv1v[nf][2]);
            float v3 = silu_f(acc[m][nf][3] + bv1v[nf][3]);
            int pk = __builtin_amdgcn_cvt_pk_fp8_f32(v0, v1, 0, false);
            pk = __builtin_amdgcn_cvt_pk_fp8_f32(v2, v3, pk, true);
            *(unsigned int*)&sF[r][boff] = (unsigned int)pk;
            acc[m][nf][0] = 0.f; acc[m][nf][1] = 0.f;
            acc[m][nf][2] = 0.f; acc[m][nf][3] = 0.f;
        }
    }
    __syncthreads();   // t visible

    // ---- GEMM2 (fp8)
    #pragma unroll
    for (int p = 0; p < 8; ++p) {
        if (p < 7) {
            wbuf[(p + 1) & 1][0] = *(const long long*)(wp2 + (p + 1) * 8192);
            wbuf[(p + 1) & 1][1] = *(const long long*)(wp2 + (p + 1) * 8192 + 512);
        }
        long long af[4];
        #pragma unroll
        for (int m = 0; m < 4; ++m) {
            int r = m * 16 + ll;
            af[m] = *(const long long*)&sF[r][(((p * 4 + lg) ^ (r & 7)) << 3)];
        }
        #pragma unroll
        for (int m = 0; m < 4; ++m)
            #pragma unroll
            for (int nf = 0; nf < 2; ++nf)
                acc[m][nf] = __builtin_amdgcn_mfma_f32_16x16x32_fp8_fp8(
                    wbuf[p & 1][nf], af[m], acc[m][nf], 0, 0, 0);
    }
    __syncthreads();   // all waves done reading sF(t)

    // ---- h = fp8(acc + b2) -> sF cells
    #pragma unroll
    for (int m = 0; m < 4; ++m) {
        int r = m * 16 + ll, rx = r & 7;
        #pragma unroll
        for (int nf = 0; nf < 2; ++nf) {
            int chunk = ((cb + nf * 16) >> 3) + (lg >> 1);
            int boff = ((chunk ^ rx) << 3) + (lg & 1) * 4;
            float v0 = acc[m][nf][0] + bv2v[nf][0];
            float v1 = acc[m][nf][1] + bv2v[nf][1];
            float v2 = acc[m][nf][2] + bv2v[nf][2];
            float v3 = acc[m][nf][3] + bv2v[nf][3];
            int pk = __builtin_amdgcn_cvt_pk_fp8_f32(v0, v1, 0, false);
            pk = __builtin_amdgcn_cvt_pk_fp8_f32(v2, v3, pk, true);
            *(unsigned int*)&sF[r][boff] = (unsigned int)pk;
        }
    }
    __syncthreads();   // h visible

    // ---- row-pass LN: 8 thr/row, rotation swizzle; residual x from global (fp8)
    {
        int rr = tid >> 3, kk = tid & 7;
        int rot = (kk + rr) & 7;
        size_t rows = ((size_t)(m0 + rr)) << 5;
        float vv[4][8];
        float s = 0.f, q = 0.f;
        #pragma unroll
        for (int i = 0; i < 4; ++i) {
            int slot = rot + 8 * i;
            uint2 hq = *(const uint2*)&sF[rr][slot << 3];
            f32x2 h0 = __builtin_amdgcn_cvt_pk_f32_fp8((int)hq.x, false);
            f32x2 h1 = __builtin_amdgcn_cvt_pk_f32_fp8((int)hq.x, true);
            f32x2 h2 = __builtin_amdgcn_cvt_pk_f32_fp8((int)hq.y, false);
            f32x2 h3 = __builtin_amdgcn_cvt_pk_f32_fp8((int)hq.y, true);
            float hf[8] = {h0[0], h0[1], h1[0], h1[1], h2[0], h2[1], h3[0], h3[1]};
            float x8[8];
            x8_load(xin, rows + slot, x8);
            #pragma unroll
            for (int j = 0; j < 8; ++j) {
                float v = hf[j] + x8[j];
                vv[i][j] = v;
                s += v; q += v * v;
            }
        }
        #pragma unroll
        for (int o = 1; o < 8; o <<= 1) {
            s += __shfl_xor(s, o, 64);
            q += __shfl_xor(q, o, 64);
        }
        float mu = s * (1.0f / HDIM);
        float var = q * (1.0f / HDIM) - mu * mu;
        float rs = rsqrtf(var + 1e-5f);
        #pragma unroll
        for (int i = 0; i < 4; ++i) {
            int slot = rot + 8 * i;
            int chunk = slot ^ (rr & 7);
            if (LAST) {
                float* xrow = xf32 + (((size_t)(m0 + rr)) << 8);
                f32x4 o0, o1;
                #pragma unroll
                for (int j = 0; j < 4; ++j) {
                    o0[j] = (vv[i][j] - mu) * rs * sGB[0][chunk * 8 + j]
                            + sGB[1][chunk * 8 + j];
                    o1[j] = (vv[i][4 + j] - mu) * rs * sGB[0][chunk * 8 + 4 + j]
                            + sGB[1][chunk * 8 + 4 + j];
                }
                *(f32x4*)&xrow[chunk * 8] = o0;
                *(f32x4*)&xrow[chunk * 8 + 4] = o1;
            } else {
                float ov[8];
                #pragma unroll
                for (int j = 0; j < 8; ++j)
                    ov[j] = (vv[i][j] - mu) * rs * sGB[0][chunk * 8 + j]
                            + sGB[1][chunk * 8 + j];
                x8_store(xout, rows + slot, ov);
            }
        }
    }
}

extern "C" void kernel_launch(void* const* d_in, const int* in_sizes, int n_in,
                              void* d_out, int out_size, void* d_ws, size_t ws_size,
                              hipStream_t stream)
{
    const int*   z    = (const int*)d_in[0];
    const float* feat = (const float*)d_in[1];
    const int*   ei   = (const int*)d_in[2];
    const float* ea   = (const float*)d_in[3];
    const int*   batch= (const int*)d_in[4];
    const float* emb  = (const float*)d_in[5];
    const float* Wf   = (const float*)d_in[6];
    const float* bfv  = (const float*)d_in[7];
    const float* g0   = (const float*)d_in[8];
    const float* b0   = (const float*)d_in[9];
    const float* We   = (const float*)d_in[10];
    const float* be   = (const float*)d_in[11];
    const float* W1   = (const float*)d_in[12];
    const float* b1   = (const float*)d_in[13];
    const float* W2   = (const float*)d_in[14];
    const float* b2   = (const float*)d_in[15];
    const float* lng  = (const float*)d_in[16];
    const float* lnb  = (const float*)d_in[17];

    float* x    = (float*)d_out;
    float* outb = (float*)d_out + (size_t)NN * HDIM;

    const size_t XBYTES = (size_t)NN * 256;           // fp8: 1B/elem
    const size_t EBYTES = (size_t)EE * 256;
    const size_t WBYTES = (size_t)LL * 65536;         // fp8 weights

    char* ws = (char*)d_ws;
    size_t o = 0;
    void* xb0 = (void*)(ws + o); o += XBYTES;
    void* xb1 = (void*)(ws + o); o += XBYTES;
    void* Ubuf = (void*)(ws + o); o += XBYTES;
    float4* eaf = (float4*)(ws + o); o += (size_t)EE * 16;
    int* srcs = (int*)(ws + o); o += (size_t)EE * 4;
    int* off = (int*)(ws + o); o += (size_t)(NN + 4) * 4;
    int* cursor = (int*)(ws + o); o += (size_t)NN * 4;
    int* deg = (int*)(ws + o); o += (size_t)NN * 4;
    int* psum = (int*)(ws + o); o += 1024;
    uchar_t* Wc1 = (uchar_t*)(ws + o); o += WBYTES;
    uchar_t* Wc2 = (uchar_t*)(ws + o); o += WBYTES;
    ushort_t* Wfc = (ushort_t*)(ws + o); o += 16384;
    void* eprec = (void*)(ws + o); o += EBYTES;
    const int use_e = (ws_size >= o) ? 1 : 0;

    prep_w_kernel<<<2048, 256, 0, stream>>>(W1, W2, Wc1, Wc2);
    prep_wf_kernel<<<32, 256, 0, stream>>>(Wf, Wfc);
    batch_out_kernel<<<782, 256, 0, stream>>>(batch, outb);
    node_init_kernel<<<NN / 64, 512, 0, stream>>>(z, feat, emb, Wfc, bfv, g0, b0, xb0);

    hipMemsetAsync(deg, 0, NN * sizeof(int), stream);
    hist_kernel<<<1563, 256, 0, stream>>>(ei, deg);
    scan_blocks_kernel<<<196, 256, 0, stream>>>(deg, off, psum);
    scan_top_kernel<<<1, 256, 0, stream>>>(psum, 196);
    scan_add_kernel<<<782, 256, 0, stream>>>(off, psum, cursor);
    scatter_kernel<<<1563, 256, 0, stream>>>(ei, ea, cursor, srcs, eaf);
    if (use_e)
        edge_mlp_kernel<<<EE / 8, 256, 0, stream>>>(eaf, We, be, eprec);

    // x ping-pong between xb0/xb1 (fp8); U (fp8) in its own buffer.
    void* xbuf[2] = {xb0, xb1};
    for (int l = 0; l < LL; ++l) {
        void* xin  = xbuf[l & 1];
        void* xout = xbuf[(l + 1) & 1];
        if (use_e)
            agg_kernel<1><<<2048, 256, 0, stream>>>(off, srcs, eprec, eaf, We, be, xin, Ubuf);
        else
            agg_kernel<0><<<2048, 256, 0, stream>>>(off, srcs, eprec, eaf, We, be, xin, Ubuf);
        if (l == LL - 1) {
            mlp_kernel<1><<<NN / 64, 512, 0, stream>>>(
                Ubuf, Wc1 + l * 65536, Wc2 + l * 65536, b1 + l * HDIM, b2 + l * HDIM,
                lng + l * HDIM, lnb + l * HDIM, xin, xout, x);
        } else {
            mlp_kernel<0><<<NN / 64, 512, 0, stream>>>(
                Ubuf, Wc1 + l * 65536, Wc2 + l * 65536, b1 + l * HDIM, b2 + l * HDIM,
                lng + l * HDIM, lnb + l * HDIM, xin, xout, nullptr);
        }
    }
}